// Round 18
// baseline (108.304 us; speedup 1.0000x reference)
//
#include <hip/hip_runtime.h>

#define NN 100000
#define EE 1600000
#define INC 128
#define OUTC 64
#define NEG_SLOPE 0.2f

#define BSH 7                 // bucket = dst >> 7 (128 nodes/bucket)
#define BNODES 128
#define NB 782                // ceil(NN/128)
#define BCAP 2560             // padded bucket capacity (mean 2048, +11 sigma)
#define SCAP2 4480            // sorted region per bucket (BCAP + 128*15 align-16 pads)
#define CHUNKA 4096           // edges per k_bin block (512 threads x 8)
#define NBLKA 391             // ceil(EE/CHUNKA)
#define NSLOT 10              // k_sort register slots: 10*256 = 2560 = BCAP

typedef __attribute__((ext_vector_type(8))) short bf16x8;
typedef __attribute__((ext_vector_type(4))) float f32x4;

__device__ __forceinline__ unsigned short f2bf(float f) {
  unsigned u = __float_as_uint(f);
  unsigned r = (u + 0x7fffu + ((u >> 16) & 1u)) >> 16;  // RNE
  return (unsigned short)r;
}
__device__ __forceinline__ float bf2f(unsigned u16) {
  return __uint_as_float(u16 << 16);
}

// ---------------- K1: Wx = x @ W^T via MFMA bf16, s_i/s_j fused ----------------
// Block 0 zeroes gcursor (R12/13: hipMemsetAsync in-graph cost ~6us serial).
// R16 lesson: never merge with bin -- shared regalloc spills MFMA accumulators.
__global__ __launch_bounds__(256) void k_gemm(
    const float* __restrict__ x, const float* __restrict__ W,
    const float* __restrict__ a, unsigned short* __restrict__ Wxh,
    float* __restrict__ s_i, float* __restrict__ s_j,
    int* __restrict__ gcursor)
{
  __shared__ __align__(16) unsigned short hs[4][32][72];  // per-wave bf16 bounce
  const int t = threadIdx.x;
  const int w = t >> 6;
  const int l = t & 63;
  const int lr = l & 15;      // A-row / B-col / C-col within 16-tile
  const int lk = l >> 4;      // k-octet group
  const int row0 = blockIdx.x * 128 + w * 32;

  if (blockIdx.x == 0) {
    for (int i = t; i < NB; i += 256) gcursor[i] = 0;
  }

  f32x4 acc[2][4];
  #pragma unroll
  for (int m = 0; m < 2; ++m)
    #pragma unroll
    for (int n = 0; n < 4; ++n) acc[m][n] = (f32x4){0.f, 0.f, 0.f, 0.f};

  #pragma unroll
  for (int ks = 0; ks < 4; ++ks) {
    const int k0 = ks * 32 + lk * 8;
    bf16x8 af[2], bfr[4];
    #pragma unroll
    for (int m = 0; m < 2; ++m) {
      int r = row0 + m * 16 + lr;
      r = (r < NN) ? r : (NN - 1);
      const float* p = &x[(size_t)r * INC + k0];
      float4 u0 = *reinterpret_cast<const float4*>(p);
      float4 u1 = *reinterpret_cast<const float4*>(p + 4);
      af[m][0] = (short)f2bf(u0.x); af[m][1] = (short)f2bf(u0.y);
      af[m][2] = (short)f2bf(u0.z); af[m][3] = (short)f2bf(u0.w);
      af[m][4] = (short)f2bf(u1.x); af[m][5] = (short)f2bf(u1.y);
      af[m][6] = (short)f2bf(u1.z); af[m][7] = (short)f2bf(u1.w);
    }
    #pragma unroll
    for (int n = 0; n < 4; ++n) {
      int c = n * 16 + lr;
      const float* p = &W[(size_t)c * INC + k0];
      float4 u0 = *reinterpret_cast<const float4*>(p);
      float4 u1 = *reinterpret_cast<const float4*>(p + 4);
      bfr[n][0] = (short)f2bf(u0.x); bfr[n][1] = (short)f2bf(u0.y);
      bfr[n][2] = (short)f2bf(u0.z); bfr[n][3] = (short)f2bf(u0.w);
      bfr[n][4] = (short)f2bf(u1.x); bfr[n][5] = (short)f2bf(u1.y);
      bfr[n][6] = (short)f2bf(u1.z); bfr[n][7] = (short)f2bf(u1.w);
    }
    #pragma unroll
    for (int m = 0; m < 2; ++m)
      #pragma unroll
      for (int n = 0; n < 4; ++n)
        acc[m][n] = __builtin_amdgcn_mfma_f32_16x16x32_bf16(af[m], bfr[n], acc[m][n], 0, 0, 0);
  }

  // fused score dots
  float a1[4], a2[4];
  #pragma unroll
  for (int n = 0; n < 4; ++n) {
    a1[n] = a[n * 16 + lr];
    a2[n] = a[OUTC + n * 16 + lr];
  }
  #pragma unroll
  for (int m = 0; m < 2; ++m)
    #pragma unroll
    for (int r = 0; r < 4; ++r) {
      float p1 = 0.f, p2 = 0.f;
      #pragma unroll
      for (int n = 0; n < 4; ++n) {
        p1 = fmaf(acc[m][n][r], a1[n], p1);
        p2 = fmaf(acc[m][n][r], a2[n], p2);
      }
      #pragma unroll
      for (int mm = 1; mm < 16; mm <<= 1) {
        p1 += __shfl_xor(p1, mm);
        p2 += __shfl_xor(p2, mm);
      }
      int rr = row0 + m * 16 + lk * 4 + r;
      if (lr == 0 && rr < NN) { s_i[rr] = p1; s_j[rr] = p2; }
    }

  // bf16 Wx store via per-wave LDS bounce -> coalesced uint4 stores
  #pragma unroll
  for (int m = 0; m < 2; ++m)
    #pragma unroll
    for (int n = 0; n < 4; ++n)
      #pragma unroll
      for (int r = 0; r < 4; ++r)
        hs[w][m * 16 + lk * 4 + r][n * 16 + lr] = f2bf(acc[m][n][r]);
  __syncthreads();
  #pragma unroll
  for (int j = 0; j < 4; ++j) {
    int idx = j * 64 + l;
    int rr = idx >> 3;
    int c8 = idx & 7;
    int node = row0 + rr;
    if (node < NN) {
      uint4 v = *reinterpret_cast<const uint4*>(&hs[w][rr][c8 * 8]);
      *reinterpret_cast<uint4*>(&Wxh[(size_t)node * OUTC + c8 * 8]) = v;
    }
  }
}

// ---------------- K2: bin edges + per-edge softmax weight (bf16 sidecar) -------
// Packed word: src (17 bits) | dl (7 bits) << 17. Rank-from-histogram.
// NEW: w = exp(leaky(s_i[dst]+s_j[src])) computed HERE -- bin runs at ~1-2
// blocks/CU latency-bound with idle VALU slots, so the 2 L2-resident random
// loads + exp per edge ride mostly free, and k_sort loses its entire
// random-gather+exp phase. w stored as bf16 sidecar binned_w.
__global__ __launch_bounds__(512) void k_bin(const int* __restrict__ src, const int* __restrict__ dst,
                                             const float* __restrict__ s_i, const float* __restrict__ s_j,
                                             int* __restrict__ gcursor, unsigned* __restrict__ binned,
                                             unsigned short* __restrict__ binned_w) {
  __shared__ int lh[1024];          // per-block bucket counts (padded to 1024)
  __shared__ int ls[1024];          // exclusive scan
  __shared__ int gb[NB];            // global base per bucket
  __shared__ int wsum[8];           // per-wave totals
  __shared__ uint2 stage[CHUNKA];   // (packed word, bucket)
  __shared__ unsigned short stagew[CHUNKA];  // bf16 w sidecar
  const int t = threadIdx.x;
  const int c0 = blockIdx.x * CHUNKA;
  const int cend = min(c0 + CHUNKA, EE);
  const int total = cend - c0;

  lh[t] = 0; lh[t + 512] = 0;
  __syncthreads();

  int esrc[8], edst[8], rnk[8];
  float ew[8];
  #pragma unroll
  for (int k = 0; k < 8; ++k) {
    int i = c0 + t + k * 512;
    bool v = i < cend;
    esrc[k] = v ? src[i] : -1;
    edst[k] = v ? dst[i] : -1;
    rnk[k] = v ? atomicAdd(&lh[edst[k] >> BSH], 1) : 0;
    float sc = v ? (s_i[edst[k]] + s_j[esrc[k]]) : 0.f;
    sc = (sc > 0.f) ? sc : NEG_SLOPE * sc;
    ew[k] = __expf(sc);
  }
  __syncthreads();

  // exclusive scan of 1024 cells: thread owns cells (2t, 2t+1); wave shfl scan
  {
    int a0 = lh[2 * t], a1 = lh[2 * t + 1];
    int s2 = a0 + a1;
    int incl = s2;
    #pragma unroll
    for (int d = 1; d < 64; d <<= 1) {
      int u = __shfl_up(incl, d);
      if ((t & 63) >= d) incl += u;
    }
    if ((t & 63) == 63) wsum[t >> 6] = incl;
    __syncthreads();
    int wv = t >> 6;
    int wbase = 0;
    #pragma unroll
    for (int k = 0; k < 8; ++k) wbase += (k < wv) ? wsum[k] : 0;
    int ex = wbase + incl - s2;
    ls[2 * t] = ex;
    ls[2 * t + 1] = ex + a0;
  }
  __syncthreads();

  #pragma unroll
  for (int k = 0; k < 8; ++k) {
    if (edst[k] >= 0) {
      int bb = edst[k] >> BSH;
      int p = ls[bb] + rnk[k];
      stage[p] = make_uint2((unsigned)esrc[k] | ((unsigned)(edst[k] & (BNODES - 1)) << 17),
                            (unsigned)bb);
      stagew[p] = f2bf(ew[k]);
    }
  }
  __syncthreads();

  for (int b = t; b < NB; b += 512) {
    int cnt = lh[b];
    if (cnt) gb[b] = atomicAdd(&gcursor[b], cnt);
  }
  __syncthreads();

  // consecutive i -> same bucket -> coalesced full-line bursts
  for (int i = t; i < total; i += 512) {
    uint2 pr = stage[i];
    int b = (int)pr.y;
    int idx = gb[b] + (i - ls[b]);
    if (idx < BCAP) {                       // clamp: never corrupt neighbors
      binned[b * BCAP + idx] = pr.x;
      binned_w[b * BCAP + idx] = stagew[i];
    }
  }
}

// ---------------- K3: per-bucket sort + offs2 + packed normalized alphas --------
// LEAN after the R18 exp-fold: coalesced meta+w reads only (no random s_j
// gather, no exp). Rank-from-histogram; 16-ALIGNED segments for the
// aggregate's 16B quad loads. stage zero-init + [0,tot) write: every read
// byte deterministic (pads: s=0, w=+0.0) -- R10 lesson.
__global__ __launch_bounds__(256) void k_sort(const int* __restrict__ gcursor,
                                              const unsigned* __restrict__ binned,
                                              const unsigned short* __restrict__ binned_w,
                                              uint2* __restrict__ offs2,
                                              unsigned* __restrict__ sorted4) {
  __shared__ int cnt128[BNODES];
  __shared__ int ex128[BNODES];
  __shared__ float den[BNODES];
  __shared__ float invd[BNODES];
  __shared__ unsigned stage[SCAP2];
  __shared__ int sW0, sTot;
  const int t = threadIdx.x;
  const int b = blockIdx.x;
  const int n0 = b << BSH;
  const int base = b * BCAP;
  const int obase = b * SCAP2;
  const int cnt = min(gcursor[b], BCAP);

  for (int i = t; i < SCAP2; i += 256) stage[i] = 0u;   // pads -> (s=0, w=+0.0)
  if (t < BNODES) {
    cnt128[t] = 0;
    den[t] = 0.f;
  }
  __syncthreads();

  // coalesced load + rank + denom in one register-staged pass
  unsigned es[NSLOT];
  int ed[NSLOT], rk[NSLOT];
  float ws[NSLOT];
  #pragma unroll
  for (int k = 0; k < NSLOT; ++k) {
    int i = t + k * 256;
    bool v = i < cnt;
    unsigned pw = v ? binned[base + i] : 0u;
    unsigned wh = v ? (unsigned)binned_w[base + i] : 0u;
    es[k] = pw & 0x1ffffu;
    ed[k] = v ? (int)(pw >> 17) : -1;
    ws[k] = bf2f(wh);
    rk[k] = 0;
    if (v) {
      rk[k] = atomicAdd(&cnt128[ed[k]], 1);
      atomicAdd(&den[ed[k]], ws[k]);
    }
  }
  __syncthreads();

  // inverse denom + exclusive scan of 16-ALIGNED counts via 2-wave shfl scan
  int cpad = 0;
  if (t < BNODES) {
    float dv = den[t];
    invd[t] = (dv > 0.f) ? 1.f / dv : 0.f;
    cpad = (cnt128[t] + 15) & ~15;
  }
  int incl = cpad;
  #pragma unroll
  for (int d = 1; d < 64; d <<= 1) {
    int u = __shfl_up(incl, d);
    if ((t & 63) >= d) incl += u;
  }
  if (t == 63) sW0 = incl;
  __syncthreads();
  if (t < BNODES) {
    int ex = incl - cpad + ((t >= 64) ? sW0 : 0);   // 16-aligned start
    ex128[t] = ex;
    int n = n0 + t;
    if (n < NN) offs2[n] = make_uint2((unsigned)(obase + ex), (unsigned)(obase + ex + cnt128[t]));
    if (t == BNODES - 1) sTot = ex + cpad;
  }
  __syncthreads();

  // scatter packed (alpha_hi15 | src): position = segment start + rank
  #pragma unroll
  for (int k = 0; k < NSLOT; ++k) {
    if (ed[k] >= 0) {
      float alpha = ws[k] * invd[ed[k]];
      unsigned abits = (__float_as_uint(alpha) + 0x10000u) & 0xfffe0000u;  // RNE to 15b
      stage[ex128[ed[k]] + rk[k]] = abits | es[k];
    }
  }
  __syncthreads();
  // write [0, tot): covers every slot the aggregate can read (16-aligned segs)
  const int tot = sTot;
  for (int i = t; i < tot; i += 256) sorted4[obase + i] = stage[i];
}

// ---------------- K4: per-node weighted aggregation + ELU ----------------
// TWO nodes per wave (32-lane halves); 4 quad-groups of 8 lanes; group g loads
// 4 edges with ONE 16B uint4 (segments 16-aligned + zero-padded, branchless),
// then issues 4 INDEPENDENT Wxh row-gathers. Reduce: 2 shfl levels.
__global__ __launch_bounds__(256) void k_aggregate(
    const uint2* __restrict__ offs2, const unsigned* __restrict__ sorted4,
    const unsigned short* __restrict__ Wxh, float* __restrict__ out)
{
  int n = blockIdx.x * 8 + (threadIdx.x >> 5);
  if (n >= NN) return;
  int l32 = threadIdx.x & 31;
  int g = l32 >> 3;                // quad slot 0..3
  unsigned cl8 = (l32 & 7) << 3;   // channel octet base
  uint2 se = offs2[n];
  int start = (int)se.x, end = (int)se.y;
  float acc[8];
  #pragma unroll
  for (int j = 0; j < 8; ++j) acc[j] = 0.f;

  for (int base = start; base < end; base += 16) {
    int i = base + 4 * g;
    uint4 pw = *reinterpret_cast<const uint4*>(&sorted4[i]);  // 16B aligned
    unsigned s0 = pw.x & 0x1ffffu, s1 = pw.y & 0x1ffffu;
    unsigned s2 = pw.z & 0x1ffffu, s3 = pw.w & 0x1ffffu;
    float w0 = __uint_as_float(pw.x & 0xfffe0000u);   // pads: bit-pattern 0 -> +0.0
    float w1 = __uint_as_float(pw.y & 0xfffe0000u);
    float w2 = __uint_as_float(pw.z & 0xfffe0000u);
    float w3 = __uint_as_float(pw.w & 0xfffe0000u);
    uint4 h0 = *reinterpret_cast<const uint4*>(&Wxh[(s0 << 6) + cl8]);
    uint4 h1 = *reinterpret_cast<const uint4*>(&Wxh[(s1 << 6) + cl8]);
    uint4 h2 = *reinterpret_cast<const uint4*>(&Wxh[(s2 << 6) + cl8]);
    uint4 h3 = *reinterpret_cast<const uint4*>(&Wxh[(s3 << 6) + cl8]);
    acc[0] = fmaf(w0, bf2f(h0.x & 0xffffu), acc[0]);
    acc[1] = fmaf(w0, bf2f(h0.x >> 16), acc[1]);
    acc[2] = fmaf(w0, bf2f(h0.y & 0xffffu), acc[2]);
    acc[3] = fmaf(w0, bf2f(h0.y >> 16), acc[3]);
    acc[4] = fmaf(w0, bf2f(h0.z & 0xffffu), acc[4]);
    acc[5] = fmaf(w0, bf2f(h0.z >> 16), acc[5]);
    acc[6] = fmaf(w0, bf2f(h0.w & 0xffffu), acc[6]);
    acc[7] = fmaf(w0, bf2f(h0.w >> 16), acc[7]);
    acc[0] = fmaf(w1, bf2f(h1.x & 0xffffu), acc[0]);
    acc[1] = fmaf(w1, bf2f(h1.x >> 16), acc[1]);
    acc[2] = fmaf(w1, bf2f(h1.y & 0xffffu), acc[2]);
    acc[3] = fmaf(w1, bf2f(h1.y >> 16), acc[3]);
    acc[4] = fmaf(w1, bf2f(h1.z & 0xffffu), acc[4]);
    acc[5] = fmaf(w1, bf2f(h1.z >> 16), acc[5]);
    acc[6] = fmaf(w1, bf2f(h1.w & 0xffffu), acc[6]);
    acc[7] = fmaf(w1, bf2f(h1.w >> 16), acc[7]);
    acc[0] = fmaf(w2, bf2f(h2.x & 0xffffu), acc[0]);
    acc[1] = fmaf(w2, bf2f(h2.x >> 16), acc[1]);
    acc[2] = fmaf(w2, bf2f(h2.y & 0xffffu), acc[2]);
    acc[3] = fmaf(w2, bf2f(h2.y >> 16), acc[3]);
    acc[4] = fmaf(w2, bf2f(h2.z & 0xffffu), acc[4]);
    acc[5] = fmaf(w2, bf2f(h2.z >> 16), acc[5]);
    acc[6] = fmaf(w2, bf2f(h2.w & 0xffffu), acc[6]);
    acc[7] = fmaf(w2, bf2f(h2.w >> 16), acc[7]);
    acc[0] = fmaf(w3, bf2f(h3.x & 0xffffu), acc[0]);
    acc[1] = fmaf(w3, bf2f(h3.x >> 16), acc[1]);
    acc[2] = fmaf(w3, bf2f(h3.y & 0xffffu), acc[2]);
    acc[3] = fmaf(w3, bf2f(h3.y >> 16), acc[3]);
    acc[4] = fmaf(w3, bf2f(h3.z & 0xffffu), acc[4]);
    acc[5] = fmaf(w3, bf2f(h3.z >> 16), acc[5]);
    acc[6] = fmaf(w3, bf2f(h3.w & 0xffffu), acc[6]);
    acc[7] = fmaf(w3, bf2f(h3.w >> 16), acc[7]);
  }

  #pragma unroll
  for (int m = 8; m <= 16; m <<= 1) {
    #pragma unroll
    for (int j = 0; j < 8; ++j) acc[j] += __shfl_xor(acc[j], m);
  }

  if (g == 0) {
    float r[8];
    #pragma unroll
    for (int j = 0; j < 8; ++j)
      r[j] = (acc[j] > 0.f) ? acc[j] : __expf(acc[j]) - 1.f;   // elu
    float4 o0 = make_float4(r[0], r[1], r[2], r[3]);
    float4 o1 = make_float4(r[4], r[5], r[6], r[7]);
    unsigned ob = ((unsigned)n << 6) + cl8;
    *reinterpret_cast<float4*>(&out[ob]) = o0;
    *reinterpret_cast<float4*>(&out[ob + 4]) = o1;
  }
}

extern "C" void kernel_launch(void* const* d_in, const int* in_sizes, int n_in,
                              void* d_out, int out_size, void* d_ws, size_t ws_size,
                              hipStream_t stream) {
  const float* x = (const float*)d_in[0];
  const int* edge = (const int*)d_in[1];   // [2, E]: row 0 = src, row 1 = dst
  const float* W = (const float*)d_in[2];
  const float* a = (const float*)d_in[3];
  const int* srcIdx = edge;
  const int* dstIdx = edge + EE;
  float* out = (float*)d_out;

  // workspace layout (~41 MB). gcursor sits right after sorted4 as the
  // read-ahead guard (always rewritten each launch; finite small ints).
  unsigned short* Wxh = (unsigned short*)d_ws;                     // N*64 bf16 = 12.8 MB
  unsigned* binned = (unsigned*)((char*)d_ws + (size_t)NN * OUTC * 2);  // NB*BCAP*4B = 8.0 MB
  unsigned short* binned_w = (unsigned short*)(binned + (size_t)NB * BCAP);  // NB*BCAP*2B = 4.0 MB
  unsigned* sorted4 = (unsigned*)(binned_w + (size_t)NB * BCAP);   // NB*SCAP2*4B = 14.0 MB
  int* gcursor = (int*)(sorted4 + (size_t)NB * SCAP2);             // NB (guard zone)
  float* s_i = (float*)(gcursor + NB);                             // N
  float* s_j = s_i + NN;                                           // N
  uint2* offs2 = (uint2*)(s_j + NN);                               // N * 8B

  k_gemm<<<NB, 256, 0, stream>>>(x, W, a, Wxh, s_i, s_j, gcursor);
  k_bin<<<NBLKA, 512, 0, stream>>>(srcIdx, dstIdx, s_i, s_j, gcursor, binned, binned_w);
  k_sort<<<NB, 256, 0, stream>>>(gcursor, binned, binned_w, offs2, sorted4);
  k_aggregate<<<(NN + 7) / 8, 256, 0, stream>>>(offs2, sorted4, Wxh, out);
}

// Round 19
// 96.173 us; speedup vs baseline: 1.1261x; 1.1261x over previous
//
#include <hip/hip_runtime.h>

#define NN 100000
#define EE 1600000
#define INC 128
#define OUTC 64
#define NEG_SLOPE 0.2f

#define BSH 7                 // bucket = dst >> 7 (128 nodes/bucket)
#define BNODES 128
#define NB 782                // ceil(NN/128)
#define BCAP 2560             // padded bucket capacity (mean 2048, +11 sigma)
#define SCAP2 4480            // sorted region per bucket (BCAP + 128*15 align-16 pads)
#define CHUNKA 6144           // edges per k_bin block (512 threads x 12)
#define NBLKA 261             // ceil(EE/CHUNKA)
#define NSLOT 10              // k_sort register slots: 10*256 = 2560 = BCAP

typedef __attribute__((ext_vector_type(8))) short bf16x8;
typedef __attribute__((ext_vector_type(4))) float f32x4;

__device__ __forceinline__ unsigned short f2bf(float f) {
  unsigned u = __float_as_uint(f);
  unsigned r = (u + 0x7fffu + ((u >> 16) & 1u)) >> 16;  // RNE
  return (unsigned short)r;
}
__device__ __forceinline__ float bf2f(unsigned u16) {
  return __uint_as_float(u16 << 16);
}

// ---------------- K1: Wx = x @ W^T via MFMA bf16, s_i/s_j fused ----------------
// Block 0 zeroes gcursor (R12/13: hipMemsetAsync in-graph cost ~6us serial).
// R16 lesson: never merge with bin -- shared regalloc spills MFMA accumulators.
// R18 lesson: never move the per-edge exp/gathers into bin -- the dependent
// s_i/s_j random loads extend bin's critical path (+12us).
__global__ __launch_bounds__(256) void k_gemm(
    const float* __restrict__ x, const float* __restrict__ W,
    const float* __restrict__ a, unsigned short* __restrict__ Wxh,
    float* __restrict__ s_i, float* __restrict__ s_j,
    int* __restrict__ gcursor)
{
  __shared__ __align__(16) unsigned short hs[4][32][72];  // per-wave bf16 bounce
  const int t = threadIdx.x;
  const int w = t >> 6;
  const int l = t & 63;
  const int lr = l & 15;      // A-row / B-col / C-col within 16-tile
  const int lk = l >> 4;      // k-octet group
  const int row0 = blockIdx.x * 128 + w * 32;

  if (blockIdx.x == 0) {
    for (int i = t; i < NB; i += 256) gcursor[i] = 0;
  }

  f32x4 acc[2][4];
  #pragma unroll
  for (int m = 0; m < 2; ++m)
    #pragma unroll
    for (int n = 0; n < 4; ++n) acc[m][n] = (f32x4){0.f, 0.f, 0.f, 0.f};

  #pragma unroll
  for (int ks = 0; ks < 4; ++ks) {
    const int k0 = ks * 32 + lk * 8;
    bf16x8 af[2], bfr[4];
    #pragma unroll
    for (int m = 0; m < 2; ++m) {
      int r = row0 + m * 16 + lr;
      r = (r < NN) ? r : (NN - 1);
      const float* p = &x[(size_t)r * INC + k0];
      float4 u0 = *reinterpret_cast<const float4*>(p);
      float4 u1 = *reinterpret_cast<const float4*>(p + 4);
      af[m][0] = (short)f2bf(u0.x); af[m][1] = (short)f2bf(u0.y);
      af[m][2] = (short)f2bf(u0.z); af[m][3] = (short)f2bf(u0.w);
      af[m][4] = (short)f2bf(u1.x); af[m][5] = (short)f2bf(u1.y);
      af[m][6] = (short)f2bf(u1.z); af[m][7] = (short)f2bf(u1.w);
    }
    #pragma unroll
    for (int n = 0; n < 4; ++n) {
      int c = n * 16 + lr;
      const float* p = &W[(size_t)c * INC + k0];
      float4 u0 = *reinterpret_cast<const float4*>(p);
      float4 u1 = *reinterpret_cast<const float4*>(p + 4);
      bfr[n][0] = (short)f2bf(u0.x); bfr[n][1] = (short)f2bf(u0.y);
      bfr[n][2] = (short)f2bf(u0.z); bfr[n][3] = (short)f2bf(u0.w);
      bfr[n][4] = (short)f2bf(u1.x); bfr[n][5] = (short)f2bf(u1.y);
      bfr[n][6] = (short)f2bf(u1.z); bfr[n][7] = (short)f2bf(u1.w);
    }
    #pragma unroll
    for (int m = 0; m < 2; ++m)
      #pragma unroll
      for (int n = 0; n < 4; ++n)
        acc[m][n] = __builtin_amdgcn_mfma_f32_16x16x32_bf16(af[m], bfr[n], acc[m][n], 0, 0, 0);
  }

  // fused score dots
  float a1[4], a2[4];
  #pragma unroll
  for (int n = 0; n < 4; ++n) {
    a1[n] = a[n * 16 + lr];
    a2[n] = a[OUTC + n * 16 + lr];
  }
  #pragma unroll
  for (int m = 0; m < 2; ++m)
    #pragma unroll
    for (int r = 0; r < 4; ++r) {
      float p1 = 0.f, p2 = 0.f;
      #pragma unroll
      for (int n = 0; n < 4; ++n) {
        p1 = fmaf(acc[m][n][r], a1[n], p1);
        p2 = fmaf(acc[m][n][r], a2[n], p2);
      }
      #pragma unroll
      for (int mm = 1; mm < 16; mm <<= 1) {
        p1 += __shfl_xor(p1, mm);
        p2 += __shfl_xor(p2, mm);
      }
      int rr = row0 + m * 16 + lk * 4 + r;
      if (lr == 0 && rr < NN) { s_i[rr] = p1; s_j[rr] = p2; }
    }

  // bf16 Wx store via per-wave LDS bounce -> coalesced uint4 stores
  #pragma unroll
  for (int m = 0; m < 2; ++m)
    #pragma unroll
    for (int n = 0; n < 4; ++n)
      #pragma unroll
      for (int r = 0; r < 4; ++r)
        hs[w][m * 16 + lk * 4 + r][n * 16 + lr] = f2bf(acc[m][n][r]);
  __syncthreads();
  #pragma unroll
  for (int j = 0; j < 4; ++j) {
    int idx = j * 64 + l;
    int rr = idx >> 3;
    int c8 = idx & 7;
    int node = row0 + rr;
    if (node < NN) {
      uint4 v = *reinterpret_cast<const uint4*>(&hs[w][rr][c8 * 8]);
      *reinterpret_cast<uint4*>(&Wxh[(size_t)node * OUTC + c8 * 8]) = v;
    }
  }
}

// ---------------- K2: bin edges into padded bucket regions (burst writes) -------
// Packed word: src (17 bits) | dl (7 bits) << 17. Bucket base implicit.
// Rank-from-histogram. CHUNKA=6144: ~7.9 edges/bucket/block -> fewer partial
// cache-line writes to binned than at 4096 (~5.2).
__global__ __launch_bounds__(512) void k_bin(const int* __restrict__ src, const int* __restrict__ dst,
                                             int* __restrict__ gcursor, unsigned* __restrict__ binned) {
  __shared__ int lh[1024];          // per-block bucket counts (padded to 1024)
  __shared__ int ls[1024];          // exclusive scan
  __shared__ int gb[NB];            // global base per bucket
  __shared__ int wsum[8];           // per-wave totals
  __shared__ uint2 stage[CHUNKA];   // (packed word, bucket)
  const int t = threadIdx.x;
  const int c0 = blockIdx.x * CHUNKA;
  const int cend = min(c0 + CHUNKA, EE);
  const int total = cend - c0;

  lh[t] = 0; lh[t + 512] = 0;
  __syncthreads();

  int esrc[12], edst[12], rnk[12];
  #pragma unroll
  for (int k = 0; k < 12; ++k) {
    int i = c0 + t + k * 512;
    bool v = i < cend;
    esrc[k] = v ? src[i] : -1;
    edst[k] = v ? dst[i] : -1;
    rnk[k] = v ? atomicAdd(&lh[edst[k] >> BSH], 1) : 0;
  }
  __syncthreads();

  // exclusive scan of 1024 cells: thread owns cells (2t, 2t+1); wave shfl scan
  {
    int a0 = lh[2 * t], a1 = lh[2 * t + 1];
    int s2 = a0 + a1;
    int incl = s2;
    #pragma unroll
    for (int d = 1; d < 64; d <<= 1) {
      int u = __shfl_up(incl, d);
      if ((t & 63) >= d) incl += u;
    }
    if ((t & 63) == 63) wsum[t >> 6] = incl;
    __syncthreads();
    int wv = t >> 6;
    int wbase = 0;
    #pragma unroll
    for (int k = 0; k < 8; ++k) wbase += (k < wv) ? wsum[k] : 0;
    int ex = wbase + incl - s2;
    ls[2 * t] = ex;
    ls[2 * t + 1] = ex + a0;
  }
  __syncthreads();

  #pragma unroll
  for (int k = 0; k < 12; ++k) {
    if (edst[k] >= 0) {
      int bb = edst[k] >> BSH;
      stage[ls[bb] + rnk[k]] =
          make_uint2((unsigned)esrc[k] | ((unsigned)(edst[k] & (BNODES - 1)) << 17),
                     (unsigned)bb);
    }
  }
  __syncthreads();

  for (int b = t; b < NB; b += 512) {
    int cnt = lh[b];
    if (cnt) gb[b] = atomicAdd(&gcursor[b], cnt);
  }
  __syncthreads();

  // consecutive i -> same bucket -> coalesced full-line bursts
  for (int i = t; i < total; i += 512) {
    uint2 pr = stage[i];
    int b = (int)pr.y;
    int idx = gb[b] + (i - ls[b]);
    if (idx < BCAP) binned[b * BCAP + idx] = pr.x;   // clamp: never corrupt neighbors
  }
}

// ---------------- K3: per-bucket sort + offs2 + packed normalized alphas --------
// Rank-from-histogram. Node segments start at 16-ALIGNED offsets so the
// aggregate can consume 4 edges per 16 B uint4 load with NO bounds checks.
// stage zero-init + [0,tot) write: every read byte deterministic (pads:
// s=0, w=+0.0) -- R10 lesson.
__global__ __launch_bounds__(256) void k_sort(const int* __restrict__ gcursor,
                                              const unsigned* __restrict__ binned,
                                              const float* __restrict__ s_i,
                                              const float* __restrict__ s_j,
                                              uint2* __restrict__ offs2,
                                              unsigned* __restrict__ sorted4) {
  __shared__ int cnt128[BNODES];
  __shared__ int ex128[BNODES];
  __shared__ float sil[BNODES];
  __shared__ float den[BNODES];
  __shared__ float invd[BNODES];
  __shared__ unsigned stage[SCAP2];
  __shared__ int sW0, sTot;
  const int t = threadIdx.x;
  const int b = blockIdx.x;
  const int n0 = b << BSH;
  const int base = b * BCAP;
  const int obase = b * SCAP2;
  const int cnt = min(gcursor[b], BCAP);

  for (int i = t; i < SCAP2; i += 256) stage[i] = 0u;   // pads -> (s=0, w=+0.0)
  if (t < BNODES) {
    cnt128[t] = 0;
    den[t] = 0.f;
    int n = n0 + t;
    sil[t] = (n < NN) ? s_i[n] : 0.f;
  }
  __syncthreads();

  // load + rank + weight + denom in one register-staged pass
  unsigned es[NSLOT];
  int ed[NSLOT], rk[NSLOT];
  float ws[NSLOT];
  #pragma unroll
  for (int k = 0; k < NSLOT; ++k) {
    int i = t + k * 256;
    bool v = i < cnt;
    unsigned pw = v ? binned[base + i] : 0u;
    es[k] = pw & 0x1ffffu;
    ed[k] = v ? (int)(pw >> 17) : -1;
    ws[k] = 0.f;
    rk[k] = 0;
    if (v) {
      rk[k] = atomicAdd(&cnt128[ed[k]], 1);
      float sc = sil[ed[k]] + s_j[es[k]];
      sc = (sc > 0.f) ? sc : NEG_SLOPE * sc;
      ws[k] = __expf(sc);
      atomicAdd(&den[ed[k]], ws[k]);
    }
  }
  __syncthreads();

  // inverse denom + exclusive scan of 16-ALIGNED counts via 2-wave shfl scan
  int cpad = 0;
  if (t < BNODES) {
    float dv = den[t];
    invd[t] = (dv > 0.f) ? 1.f / dv : 0.f;
    cpad = (cnt128[t] + 15) & ~15;
  }
  int incl = cpad;
  #pragma unroll
  for (int d = 1; d < 64; d <<= 1) {
    int u = __shfl_up(incl, d);
    if ((t & 63) >= d) incl += u;
  }
  if (t == 63) sW0 = incl;
  __syncthreads();
  if (t < BNODES) {
    int ex = incl - cpad + ((t >= 64) ? sW0 : 0);   // 16-aligned start
    ex128[t] = ex;
    int n = n0 + t;
    if (n < NN) offs2[n] = make_uint2((unsigned)(obase + ex), (unsigned)(obase + ex + cnt128[t]));
    if (t == BNODES - 1) sTot = ex + cpad;
  }
  __syncthreads();

  // scatter packed (alpha_hi15 | src): position = segment start + rank
  #pragma unroll
  for (int k = 0; k < NSLOT; ++k) {
    if (ed[k] >= 0) {
      float alpha = ws[k] * invd[ed[k]];
      unsigned abits = (__float_as_uint(alpha) + 0x10000u) & 0xfffe0000u;  // RNE to 15b
      stage[ex128[ed[k]] + rk[k]] = abits | es[k];
    }
  }
  __syncthreads();
  // write [0, tot): covers every slot the aggregate can read (16-aligned segs)
  const int tot = sTot;
  for (int i = t; i < tot; i += 256) sorted4[obase + i] = stage[i];
}

// ---------------- K4: per-node weighted aggregation + ELU ----------------
// TWO nodes per wave (32-lane halves); 4 quad-groups of 8 lanes; group g loads
// 4 edges with ONE 16B uint4 (segments 16-aligned + zero-padded, branchless),
// then issues 4 INDEPENDENT Wxh row-gathers. Reduce: 2 shfl levels.
__global__ __launch_bounds__(256) void k_aggregate(
    const uint2* __restrict__ offs2, const unsigned* __restrict__ sorted4,
    const unsigned short* __restrict__ Wxh, float* __restrict__ out)
{
  int n = blockIdx.x * 8 + (threadIdx.x >> 5);
  if (n >= NN) return;
  int l32 = threadIdx.x & 31;
  int g = l32 >> 3;                // quad slot 0..3
  unsigned cl8 = (l32 & 7) << 3;   // channel octet base
  uint2 se = offs2[n];
  int start = (int)se.x, end = (int)se.y;
  float acc[8];
  #pragma unroll
  for (int j = 0; j < 8; ++j) acc[j] = 0.f;

  for (int base = start; base < end; base += 16) {
    int i = base + 4 * g;
    uint4 pw = *reinterpret_cast<const uint4*>(&sorted4[i]);  // 16B aligned
    unsigned s0 = pw.x & 0x1ffffu, s1 = pw.y & 0x1ffffu;
    unsigned s2 = pw.z & 0x1ffffu, s3 = pw.w & 0x1ffffu;
    float w0 = __uint_as_float(pw.x & 0xfffe0000u);   // pads: bit-pattern 0 -> +0.0
    float w1 = __uint_as_float(pw.y & 0xfffe0000u);
    float w2 = __uint_as_float(pw.z & 0xfffe0000u);
    float w3 = __uint_as_float(pw.w & 0xfffe0000u);
    uint4 h0 = *reinterpret_cast<const uint4*>(&Wxh[(s0 << 6) + cl8]);
    uint4 h1 = *reinterpret_cast<const uint4*>(&Wxh[(s1 << 6) + cl8]);
    uint4 h2 = *reinterpret_cast<const uint4*>(&Wxh[(s2 << 6) + cl8]);
    uint4 h3 = *reinterpret_cast<const uint4*>(&Wxh[(s3 << 6) + cl8]);
    acc[0] = fmaf(w0, bf2f(h0.x & 0xffffu), acc[0]);
    acc[1] = fmaf(w0, bf2f(h0.x >> 16), acc[1]);
    acc[2] = fmaf(w0, bf2f(h0.y & 0xffffu), acc[2]);
    acc[3] = fmaf(w0, bf2f(h0.y >> 16), acc[3]);
    acc[4] = fmaf(w0, bf2f(h0.z & 0xffffu), acc[4]);
    acc[5] = fmaf(w0, bf2f(h0.z >> 16), acc[5]);
    acc[6] = fmaf(w0, bf2f(h0.w & 0xffffu), acc[6]);
    acc[7] = fmaf(w0, bf2f(h0.w >> 16), acc[7]);
    acc[0] = fmaf(w1, bf2f(h1.x & 0xffffu), acc[0]);
    acc[1] = fmaf(w1, bf2f(h1.x >> 16), acc[1]);
    acc[2] = fmaf(w1, bf2f(h1.y & 0xffffu), acc[2]);
    acc[3] = fmaf(w1, bf2f(h1.y >> 16), acc[3]);
    acc[4] = fmaf(w1, bf2f(h1.z & 0xffffu), acc[4]);
    acc[5] = fmaf(w1, bf2f(h1.z >> 16), acc[5]);
    acc[6] = fmaf(w1, bf2f(h1.w & 0xffffu), acc[6]);
    acc[7] = fmaf(w1, bf2f(h1.w >> 16), acc[7]);
    acc[0] = fmaf(w2, bf2f(h2.x & 0xffffu), acc[0]);
    acc[1] = fmaf(w2, bf2f(h2.x >> 16), acc[1]);
    acc[2] = fmaf(w2, bf2f(h2.y & 0xffffu), acc[2]);
    acc[3] = fmaf(w2, bf2f(h2.y >> 16), acc[3]);
    acc[4] = fmaf(w2, bf2f(h2.z & 0xffffu), acc[4]);
    acc[5] = fmaf(w2, bf2f(h2.z >> 16), acc[5]);
    acc[6] = fmaf(w2, bf2f(h2.w & 0xffffu), acc[6]);
    acc[7] = fmaf(w2, bf2f(h2.w >> 16), acc[7]);
    acc[0] = fmaf(w3, bf2f(h3.x & 0xffffu), acc[0]);
    acc[1] = fmaf(w3, bf2f(h3.x >> 16), acc[1]);
    acc[2] = fmaf(w3, bf2f(h3.y & 0xffffu), acc[2]);
    acc[3] = fmaf(w3, bf2f(h3.y >> 16), acc[3]);
    acc[4] = fmaf(w3, bf2f(h3.z & 0xffffu), acc[4]);
    acc[5] = fmaf(w3, bf2f(h3.z >> 16), acc[5]);
    acc[6] = fmaf(w3, bf2f(h3.w & 0xffffu), acc[6]);
    acc[7] = fmaf(w3, bf2f(h3.w >> 16), acc[7]);
  }

  #pragma unroll
  for (int m = 8; m <= 16; m <<= 1) {
    #pragma unroll
    for (int j = 0; j < 8; ++j) acc[j] += __shfl_xor(acc[j], m);
  }

  if (g == 0) {
    float r[8];
    #pragma unroll
    for (int j = 0; j < 8; ++j)
      r[j] = (acc[j] > 0.f) ? acc[j] : __expf(acc[j]) - 1.f;   // elu
    float4 o0 = make_float4(r[0], r[1], r[2], r[3]);
    float4 o1 = make_float4(r[4], r[5], r[6], r[7]);
    unsigned ob = ((unsigned)n << 6) + cl8;
    *reinterpret_cast<float4*>(&out[ob]) = o0;
    *reinterpret_cast<float4*>(&out[ob + 4]) = o1;
  }
}

extern "C" void kernel_launch(void* const* d_in, const int* in_sizes, int n_in,
                              void* d_out, int out_size, void* d_ws, size_t ws_size,
                              hipStream_t stream) {
  const float* x = (const float*)d_in[0];
  const int* edge = (const int*)d_in[1];   // [2, E]: row 0 = src, row 1 = dst
  const float* W = (const float*)d_in[2];
  const float* a = (const float*)d_in[3];
  const int* srcIdx = edge;
  const int* dstIdx = edge + EE;
  float* out = (float*)d_out;

  // workspace layout (~37 MB). gcursor sits right after sorted4 as the
  // read-ahead guard (always rewritten each launch; finite small ints).
  unsigned short* Wxh = (unsigned short*)d_ws;                     // N*64 bf16 = 12.8 MB
  unsigned* binned = (unsigned*)((char*)d_ws + (size_t)NN * OUTC * 2);  // NB*BCAP*4B = 8.0 MB
  unsigned* sorted4 = binned + (size_t)NB * BCAP;                  // NB*SCAP2*4B = 14.0 MB
  int* gcursor = (int*)(sorted4 + (size_t)NB * SCAP2);             // NB (guard zone)
  float* s_i = (float*)(gcursor + NB);                             // N
  float* s_j = s_i + NN;                                           // N
  uint2* offs2 = (uint2*)(s_j + NN);                               // N * 8B

  k_gemm<<<NB, 256, 0, stream>>>(x, W, a, Wxh, s_i, s_j, gcursor);
  k_bin<<<NBLKA, 512, 0, stream>>>(srcIdx, dstIdx, gcursor, binned);
  k_sort<<<NB, 256, 0, stream>>>(gcursor, binned, s_i, s_j, offs2, sorted4);
  k_aggregate<<<(NN + 7) / 8, 256, 0, stream>>>(offs2, sorted4, Wxh, out);
}

// Round 20
// 91.900 us; speedup vs baseline: 1.1785x; 1.0465x over previous
//
#include <hip/hip_runtime.h>

#define NN 100000
#define EE 1600000
#define INC 128
#define OUTC 64
#define NEG_SLOPE 0.2f

#define BSH 7                 // bucket = dst >> 7 (128 nodes/bucket)
#define BNODES 128
#define NB 782                // ceil(NN/128)
#define BCAP 2560             // padded bucket capacity (mean 2048, +11 sigma)
#define SCAP2 4480            // sorted region per bucket (BCAP + 128*15 align-16 pads)
#define CHUNKA 4096           // edges per bin-role block (256 threads x 16)
#define NBLKA 391             // ceil(EE/CHUNKA)
#define NBLKG (NB + NBLKA)    // merged grid: 782 gemm + 391 bin = 1173
#define NSLOT 10              // k_sort register slots: 10*256 = 2560 = BCAP

typedef __attribute__((ext_vector_type(8))) short bf16x8;
typedef __attribute__((ext_vector_type(4))) float f32x4;

__device__ __forceinline__ unsigned short f2bf(float f) {
  unsigned u = __float_as_uint(f);
  unsigned r = (u + 0x7fffu + ((u >> 16) & 1u)) >> 16;  // RNE
  return (unsigned short)r;
}
__device__ __forceinline__ float bf2f(unsigned u16) {
  return __uint_as_float(u16 << 16);
}

// ---------------- K0: zero bucket cursors (must precede k_gb's bin role) -------
__global__ __launch_bounds__(256) void k_zero(int* __restrict__ gcursor) {
  for (int i = threadIdx.x; i < NB; i += 256) gcursor[i] = 0;
}

// ---------------- K1: gemm-role || bin-role, INTERLEAVED (R16 retry, fixed) ----
// R16 failed because (a) shared regalloc squeezed gemm to 64 VGPR -> MFMA acc
// spill, and (b) all gemm blocks dispatched before any bin block -> no
// co-residency. Fixes: amdgpu_waves_per_eu(1,3) caps occupancy so ~170 VGPRs
// stay available (no spill), and roles interleave (blockIdx%3==2 -> bin) so
// each CU hosts both pipes from t=0. Verification: VGPR_Count ~140, not 64.
__global__ __launch_bounds__(256)
__attribute__((amdgpu_waves_per_eu(1, 3)))
void k_gb(
    const float* __restrict__ x, const float* __restrict__ W,
    const float* __restrict__ a, unsigned short* __restrict__ Wxh,
    float* __restrict__ s_i, float* __restrict__ s_j,
    const int* __restrict__ src, const int* __restrict__ dst,
    int* __restrict__ gcursor, unsigned* __restrict__ binned)
{
  __shared__ __align__(16) char smem[44240];   // union: gemm 18.4KB | bin 43.2KB
  const int t = threadIdx.x;
  const int bid = blockIdx.x;
  const bool isBin = (bid % 3 == 2);

  if (!isBin) {
    // ================= gemm role: Wx = x @ W^T via MFMA, s_i/s_j fused =======
    const int gi = (bid / 3) * 2 + (bid % 3);   // 0..781, each exactly once
    unsigned short (*hs)[32][72] = reinterpret_cast<unsigned short(*)[32][72]>(smem);
    const int w = t >> 6;
    const int l = t & 63;
    const int lr = l & 15;
    const int lk = l >> 4;
    const int row0 = gi * 128 + w * 32;

    f32x4 acc[2][4];
    #pragma unroll
    for (int m = 0; m < 2; ++m)
      #pragma unroll
      for (int n = 0; n < 4; ++n) acc[m][n] = (f32x4){0.f, 0.f, 0.f, 0.f};

    #pragma unroll
    for (int ks = 0; ks < 4; ++ks) {
      const int k0 = ks * 32 + lk * 8;
      bf16x8 af[2], bfr[4];
      #pragma unroll
      for (int m = 0; m < 2; ++m) {
        int r = row0 + m * 16 + lr;
        r = (r < NN) ? r : (NN - 1);
        const float* p = &x[(size_t)r * INC + k0];
        float4 u0 = *reinterpret_cast<const float4*>(p);
        float4 u1 = *reinterpret_cast<const float4*>(p + 4);
        af[m][0] = (short)f2bf(u0.x); af[m][1] = (short)f2bf(u0.y);
        af[m][2] = (short)f2bf(u0.z); af[m][3] = (short)f2bf(u0.w);
        af[m][4] = (short)f2bf(u1.x); af[m][5] = (short)f2bf(u1.y);
        af[m][6] = (short)f2bf(u1.z); af[m][7] = (short)f2bf(u1.w);
      }
      #pragma unroll
      for (int n = 0; n < 4; ++n) {
        int c = n * 16 + lr;
        const float* p = &W[(size_t)c * INC + k0];
        float4 u0 = *reinterpret_cast<const float4*>(p);
        float4 u1 = *reinterpret_cast<const float4*>(p + 4);
        bfr[n][0] = (short)f2bf(u0.x); bfr[n][1] = (short)f2bf(u0.y);
        bfr[n][2] = (short)f2bf(u0.z); bfr[n][3] = (short)f2bf(u0.w);
        bfr[n][4] = (short)f2bf(u1.x); bfr[n][5] = (short)f2bf(u1.y);
        bfr[n][6] = (short)f2bf(u1.z); bfr[n][7] = (short)f2bf(u1.w);
      }
      #pragma unroll
      for (int m = 0; m < 2; ++m)
        #pragma unroll
        for (int n = 0; n < 4; ++n)
          acc[m][n] = __builtin_amdgcn_mfma_f32_16x16x32_bf16(af[m], bfr[n], acc[m][n], 0, 0, 0);
    }

    // fused score dots
    float a1[4], a2[4];
    #pragma unroll
    for (int n = 0; n < 4; ++n) {
      a1[n] = a[n * 16 + lr];
      a2[n] = a[OUTC + n * 16 + lr];
    }
    #pragma unroll
    for (int m = 0; m < 2; ++m)
      #pragma unroll
      for (int r = 0; r < 4; ++r) {
        float p1 = 0.f, p2 = 0.f;
        #pragma unroll
        for (int n = 0; n < 4; ++n) {
          p1 = fmaf(acc[m][n][r], a1[n], p1);
          p2 = fmaf(acc[m][n][r], a2[n], p2);
        }
        #pragma unroll
        for (int mm = 1; mm < 16; mm <<= 1) {
          p1 += __shfl_xor(p1, mm);
          p2 += __shfl_xor(p2, mm);
        }
        int rr = row0 + m * 16 + lk * 4 + r;
        if (lr == 0 && rr < NN) { s_i[rr] = p1; s_j[rr] = p2; }
      }

    // bf16 Wx store via per-wave LDS bounce -> coalesced uint4 stores
    #pragma unroll
    for (int m = 0; m < 2; ++m)
      #pragma unroll
      for (int n = 0; n < 4; ++n)
        #pragma unroll
        for (int r = 0; r < 4; ++r)
          hs[w][m * 16 + lk * 4 + r][n * 16 + lr] = f2bf(acc[m][n][r]);
    __syncthreads();
    #pragma unroll
    for (int j = 0; j < 4; ++j) {
      int idx = j * 64 + t % 64 + (w * 64 - w * 64);  // = j*64 + l
      idx = j * 64 + l;
      int rr = idx >> 3;
      int c8 = idx & 7;
      int node = row0 + rr;
      if (node < NN) {
        uint4 v = *reinterpret_cast<const uint4*>(&hs[w][rr][c8 * 8]);
        *reinterpret_cast<uint4*>(&Wxh[(size_t)node * OUTC + c8 * 8]) = v;
      }
    }
  } else {
    // ================= bin role: bucket-bin 4096 edges (burst writes) ========
    // Packed word: src (17b) | dl (7b) << 17. Rank-from-histogram.
    const int bi = bid / 3;                  // 0..390
    int* lh = reinterpret_cast<int*>(smem);                 // 1024 ints
    int* ls = lh + 1024;                                    // 1024 ints
    int* gb = ls + 1024;                                    // 784 ints
    uint2* stage = reinterpret_cast<uint2*>(smem + 11328);  // 4096 uint2 (8B-aligned)
    __shared__ int wsum[4];
    const int c0 = bi * CHUNKA;
    const int cend = min(c0 + CHUNKA, EE);
    const int total = cend - c0;

    #pragma unroll
    for (int k = 0; k < 4; ++k) lh[t + k * 256] = 0;
    __syncthreads();

    int esrc[16], edst[16], rnk[16];
    #pragma unroll
    for (int k = 0; k < 16; ++k) {
      int i = c0 + t + k * 256;
      bool v = i < cend;
      esrc[k] = v ? src[i] : -1;
      edst[k] = v ? dst[i] : -1;
      rnk[k] = v ? atomicAdd(&lh[edst[k] >> BSH], 1) : 0;
    }
    __syncthreads();

    // exclusive scan of 1024 cells: thread owns cells 4t..4t+3; wave shfl scan
    {
      int a0 = lh[4 * t], a1 = lh[4 * t + 1], a2 = lh[4 * t + 2], a3 = lh[4 * t + 3];
      int s4 = a0 + a1 + a2 + a3;
      int incl = s4;
      #pragma unroll
      for (int d = 1; d < 64; d <<= 1) {
        int u = __shfl_up(incl, d);
        if ((t & 63) >= d) incl += u;
      }
      if ((t & 63) == 63) wsum[t >> 6] = incl;
      __syncthreads();
      int wv = t >> 6;
      int wbase = 0;
      #pragma unroll
      for (int k = 0; k < 4; ++k) wbase += (k < wv) ? wsum[k] : 0;
      int ex = wbase + incl - s4;
      ls[4 * t] = ex;
      ls[4 * t + 1] = ex + a0;
      ls[4 * t + 2] = ex + a0 + a1;
      ls[4 * t + 3] = ex + a0 + a1 + a2;
    }
    __syncthreads();

    #pragma unroll
    for (int k = 0; k < 16; ++k) {
      if (edst[k] >= 0) {
        int bb = edst[k] >> BSH;
        stage[ls[bb] + rnk[k]] =
            make_uint2((unsigned)esrc[k] | ((unsigned)(edst[k] & (BNODES - 1)) << 17),
                       (unsigned)bb);
      }
    }
    __syncthreads();

    for (int b = t; b < NB; b += 256) {
      int cnt = lh[b];
      if (cnt) gb[b] = atomicAdd(&gcursor[b], cnt);
    }
    __syncthreads();

    // consecutive i -> same bucket -> coalesced full-line bursts
    for (int i = t; i < total; i += 256) {
      uint2 pr = stage[i];
      int b = (int)pr.y;
      int idx = gb[b] + (i - ls[b]);
      if (idx < BCAP) binned[b * BCAP + idx] = pr.x;   // clamp: never corrupt neighbors
    }
  }
}

// ---------------- K2: per-bucket sort + offs2 + packed normalized alphas --------
// Rank-from-histogram. Node segments start at 16-ALIGNED offsets so the
// aggregate can consume 4 edges per 16 B uint4 load with NO bounds checks.
// stage zero-init + [0,tot) write: every read byte deterministic (pads:
// s=0, w=+0.0) -- R10 lesson.
__global__ __launch_bounds__(256) void k_sort(const int* __restrict__ gcursor,
                                              const unsigned* __restrict__ binned,
                                              const float* __restrict__ s_i,
                                              const float* __restrict__ s_j,
                                              uint2* __restrict__ offs2,
                                              unsigned* __restrict__ sorted4) {
  __shared__ int cnt128[BNODES];
  __shared__ int ex128[BNODES];
  __shared__ float sil[BNODES];
  __shared__ float den[BNODES];
  __shared__ float invd[BNODES];
  __shared__ unsigned stage[SCAP2];
  __shared__ int sW0, sTot;
  const int t = threadIdx.x;
  const int b = blockIdx.x;
  const int n0 = b << BSH;
  const int base = b * BCAP;
  const int obase = b * SCAP2;
  const int cnt = min(gcursor[b], BCAP);

  for (int i = t; i < SCAP2; i += 256) stage[i] = 0u;   // pads -> (s=0, w=+0.0)
  if (t < BNODES) {
    cnt128[t] = 0;
    den[t] = 0.f;
    int n = n0 + t;
    sil[t] = (n < NN) ? s_i[n] : 0.f;
  }
  __syncthreads();

  // load + rank + weight + denom in one register-staged pass
  unsigned es[NSLOT];
  int ed[NSLOT], rk[NSLOT];
  float ws[NSLOT];
  #pragma unroll
  for (int k = 0; k < NSLOT; ++k) {
    int i = t + k * 256;
    bool v = i < cnt;
    unsigned pw = v ? binned[base + i] : 0u;
    es[k] = pw & 0x1ffffu;
    ed[k] = v ? (int)(pw >> 17) : -1;
    ws[k] = 0.f;
    rk[k] = 0;
    if (v) {
      rk[k] = atomicAdd(&cnt128[ed[k]], 1);
      float sc = sil[ed[k]] + s_j[es[k]];
      sc = (sc > 0.f) ? sc : NEG_SLOPE * sc;
      ws[k] = __expf(sc);
      atomicAdd(&den[ed[k]], ws[k]);
    }
  }
  __syncthreads();

  // inverse denom + exclusive scan of 16-ALIGNED counts via 2-wave shfl scan
  int cpad = 0;
  if (t < BNODES) {
    float dv = den[t];
    invd[t] = (dv > 0.f) ? 1.f / dv : 0.f;
    cpad = (cnt128[t] + 15) & ~15;
  }
  int incl = cpad;
  #pragma unroll
  for (int d = 1; d < 64; d <<= 1) {
    int u = __shfl_up(incl, d);
    if ((t & 63) >= d) incl += u;
  }
  if (t == 63) sW0 = incl;
  __syncthreads();
  if (t < BNODES) {
    int ex = incl - cpad + ((t >= 64) ? sW0 : 0);   // 16-aligned start
    ex128[t] = ex;
    int n = n0 + t;
    if (n < NN) offs2[n] = make_uint2((unsigned)(obase + ex), (unsigned)(obase + ex + cnt128[t]));
    if (t == BNODES - 1) sTot = ex + cpad;
  }
  __syncthreads();

  // scatter packed (alpha_hi15 | src): position = segment start + rank
  #pragma unroll
  for (int k = 0; k < NSLOT; ++k) {
    if (ed[k] >= 0) {
      float alpha = ws[k] * invd[ed[k]];
      unsigned abits = (__float_as_uint(alpha) + 0x10000u) & 0xfffe0000u;  // RNE to 15b
      stage[ex128[ed[k]] + rk[k]] = abits | es[k];
    }
  }
  __syncthreads();
  // write [0, tot): covers every slot the aggregate can read (16-aligned segs)
  const int tot = sTot;
  for (int i = t; i < tot; i += 256) sorted4[obase + i] = stage[i];
}

// ---------------- K3: per-node weighted aggregation + ELU ----------------
// TWO nodes per wave (32-lane halves); 4 quad-groups of 8 lanes; group g loads
// 4 edges with ONE 16B uint4 (segments 16-aligned + zero-padded, branchless),
// then issues 4 INDEPENDENT Wxh row-gathers. Reduce: 2 shfl levels.
__global__ __launch_bounds__(256) void k_aggregate(
    const uint2* __restrict__ offs2, const unsigned* __restrict__ sorted4,
    const unsigned short* __restrict__ Wxh, float* __restrict__ out)
{
  int n = blockIdx.x * 8 + (threadIdx.x >> 5);
  if (n >= NN) return;
  int l32 = threadIdx.x & 31;
  int g = l32 >> 3;                // quad slot 0..3
  unsigned cl8 = (l32 & 7) << 3;   // channel octet base
  uint2 se = offs2[n];
  int start = (int)se.x, end = (int)se.y;
  float acc[8];
  #pragma unroll
  for (int j = 0; j < 8; ++j) acc[j] = 0.f;

  for (int base = start; base < end; base += 16) {
    int i = base + 4 * g;
    uint4 pw = *reinterpret_cast<const uint4*>(&sorted4[i]);  // 16B aligned
    unsigned s0 = pw.x & 0x1ffffu, s1 = pw.y & 0x1ffffu;
    unsigned s2 = pw.z & 0x1ffffu, s3 = pw.w & 0x1ffffu;
    float w0 = __uint_as_float(pw.x & 0xfffe0000u);   // pads: bit-pattern 0 -> +0.0
    float w1 = __uint_as_float(pw.y & 0xfffe0000u);
    float w2 = __uint_as_float(pw.z & 0xfffe0000u);
    float w3 = __uint_as_float(pw.w & 0xfffe0000u);
    uint4 h0 = *reinterpret_cast<const uint4*>(&Wxh[(s0 << 6) + cl8]);
    uint4 h1 = *reinterpret_cast<const uint4*>(&Wxh[(s1 << 6) + cl8]);
    uint4 h2 = *reinterpret_cast<const uint4*>(&Wxh[(s2 << 6) + cl8]);
    uint4 h3 = *reinterpret_cast<const uint4*>(&Wxh[(s3 << 6) + cl8]);
    acc[0] = fmaf(w0, bf2f(h0.x & 0xffffu), acc[0]);
    acc[1] = fmaf(w0, bf2f(h0.x >> 16), acc[1]);
    acc[2] = fmaf(w0, bf2f(h0.y & 0xffffu), acc[2]);
    acc[3] = fmaf(w0, bf2f(h0.y >> 16), acc[3]);
    acc[4] = fmaf(w0, bf2f(h0.z & 0xffffu), acc[4]);
    acc[5] = fmaf(w0, bf2f(h0.z >> 16), acc[5]);
    acc[6] = fmaf(w0, bf2f(h0.w & 0xffffu), acc[6]);
    acc[7] = fmaf(w0, bf2f(h0.w >> 16), acc[7]);
    acc[0] = fmaf(w1, bf2f(h1.x & 0xffffu), acc[0]);
    acc[1] = fmaf(w1, bf2f(h1.x >> 16), acc[1]);
    acc[2] = fmaf(w1, bf2f(h1.y & 0xffffu), acc[2]);
    acc[3] = fmaf(w1, bf2f(h1.y >> 16), acc[3]);
    acc[4] = fmaf(w1, bf2f(h1.z & 0xffffu), acc[4]);
    acc[5] = fmaf(w1, bf2f(h1.z >> 16), acc[5]);
    acc[6] = fmaf(w1, bf2f(h1.w & 0xffffu), acc[6]);
    acc[7] = fmaf(w1, bf2f(h1.w >> 16), acc[7]);
    acc[0] = fmaf(w2, bf2f(h2.x & 0xffffu), acc[0]);
    acc[1] = fmaf(w2, bf2f(h2.x >> 16), acc[1]);
    acc[2] = fmaf(w2, bf2f(h2.y & 0xffffu), acc[2]);
    acc[3] = fmaf(w2, bf2f(h2.y >> 16), acc[3]);
    acc[4] = fmaf(w2, bf2f(h2.z & 0xffffu), acc[4]);
    acc[5] = fmaf(w2, bf2f(h2.z >> 16), acc[5]);
    acc[6] = fmaf(w2, bf2f(h2.w & 0xffffu), acc[6]);
    acc[7] = fmaf(w2, bf2f(h2.w >> 16), acc[7]);
    acc[0] = fmaf(w3, bf2f(h3.x & 0xffffu), acc[0]);
    acc[1] = fmaf(w3, bf2f(h3.x >> 16), acc[1]);
    acc[2] = fmaf(w3, bf2f(h3.y & 0xffffu), acc[2]);
    acc[3] = fmaf(w3, bf2f(h3.y >> 16), acc[3]);
    acc[4] = fmaf(w3, bf2f(h3.z & 0xffffu), acc[4]);
    acc[5] = fmaf(w3, bf2f(h3.z >> 16), acc[5]);
    acc[6] = fmaf(w3, bf2f(h3.w & 0xffffu), acc[6]);
    acc[7] = fmaf(w3, bf2f(h3.w >> 16), acc[7]);
  }

  #pragma unroll
  for (int m = 8; m <= 16; m <<= 1) {
    #pragma unroll
    for (int j = 0; j < 8; ++j) acc[j] += __shfl_xor(acc[j], m);
  }

  if (g == 0) {
    float r[8];
    #pragma unroll
    for (int j = 0; j < 8; ++j)
      r[j] = (acc[j] > 0.f) ? acc[j] : __expf(acc[j]) - 1.f;   // elu
    float4 o0 = make_float4(r[0], r[1], r[2], r[3]);
    float4 o1 = make_float4(r[4], r[5], r[6], r[7]);
    unsigned ob = ((unsigned)n << 6) + cl8;
    *reinterpret_cast<float4*>(&out[ob]) = o0;
    *reinterpret_cast<float4*>(&out[ob + 4]) = o1;
  }
}

extern "C" void kernel_launch(void* const* d_in, const int* in_sizes, int n_in,
                              void* d_out, int out_size, void* d_ws, size_t ws_size,
                              hipStream_t stream) {
  const float* x = (const float*)d_in[0];
  const int* edge = (const int*)d_in[1];   // [2, E]: row 0 = src, row 1 = dst
  const float* W = (const float*)d_in[2];
  const float* a = (const float*)d_in[3];
  const int* srcIdx = edge;
  const int* dstIdx = edge + EE;
  float* out = (float*)d_out;

  // workspace layout (~37 MB). gcursor sits right after sorted4 as the
  // read-ahead guard (always rewritten each launch; finite small ints).
  unsigned short* Wxh = (unsigned short*)d_ws;                     // N*64 bf16 = 12.8 MB
  unsigned* binned = (unsigned*)((char*)d_ws + (size_t)NN * OUTC * 2);  // NB*BCAP*4B = 8.0 MB
  unsigned* sorted4 = binned + (size_t)NB * BCAP;                  // NB*SCAP2*4B = 14.0 MB
  int* gcursor = (int*)(sorted4 + (size_t)NB * SCAP2);             // NB (guard zone)
  float* s_i = (float*)(gcursor + NB);                             // N
  float* s_j = s_i + NN;                                           // N
  uint2* offs2 = (uint2*)(s_j + NN);                               // N * 8B

  k_zero<<<1, 256, 0, stream>>>(gcursor);
  k_gb<<<NBLKG, 256, 0, stream>>>(x, W, a, Wxh, s_i, s_j, srcIdx, dstIdx, gcursor, binned);
  k_sort<<<NB, 256, 0, stream>>>(gcursor, binned, s_i, s_j, offs2, sorted4);
  k_aggregate<<<(NN + 7) / 8, 256, 0, stream>>>(offs2, sorted4, Wxh, out);
}

// Round 21
// 91.758 us; speedup vs baseline: 1.1803x; 1.0015x over previous
//
#include <hip/hip_runtime.h>

#define NN 100000
#define EE 1600000
#define INC 128
#define OUTC 64
#define NEG_SLOPE 0.2f

#define BSH 7                 // bucket = dst >> 7 (128 nodes/bucket)
#define BNODES 128
#define NB 782                // ceil(NN/128)
#define BCAP 2560             // padded bucket capacity (mean 2048, +11 sigma)
#define CHUNKA 4096           // edges per bin-role block (256 threads x 16)
#define NBLKA 391             // ceil(EE/CHUNKA)
#define NBLKG (NB + NBLKA)    // merged grid: 782 gemm + 391 bin = 1173
#define NSLOT 10              // k_sa sort-phase register slots: 10*256 = 2560 = BCAP

typedef __attribute__((ext_vector_type(8))) short bf16x8;
typedef __attribute__((ext_vector_type(4))) float f32x4;

__device__ __forceinline__ unsigned short f2bf(float f) {
  unsigned u = __float_as_uint(f);
  unsigned r = (u + 0x7fffu + ((u >> 16) & 1u)) >> 16;  // RNE
  return (unsigned short)r;
}
__device__ __forceinline__ float bf2f(unsigned u16) {
  return __uint_as_float(u16 << 16);
}

// ---------------- K0: zero bucket cursors (must precede k_gb's bin role) -------
__global__ __launch_bounds__(256) void k_zero(int* __restrict__ gcursor) {
  for (int i = threadIdx.x; i < NB; i += 256) gcursor[i] = 0;
}

// ---------------- K1: gemm-role || bin-role, INTERLEAVED --------------------
// R20 lesson: the win here is dispatch-gap elimination + partial overlap (the
// waves_per_eu hint did NOT restore gemm's VGPR budget -- still ~68 VGPR --
// but total improved anyway). Kept as-is from R20.
__global__ __launch_bounds__(256)
__attribute__((amdgpu_waves_per_eu(1, 3)))
void k_gb(
    const float* __restrict__ x, const float* __restrict__ W,
    const float* __restrict__ a, unsigned short* __restrict__ Wxh,
    float* __restrict__ s_i, float* __restrict__ s_j,
    const int* __restrict__ src, const int* __restrict__ dst,
    int* __restrict__ gcursor, unsigned* __restrict__ binned)
{
  __shared__ __align__(16) char smem[44240];   // union: gemm 18.4KB | bin 43.2KB
  const int t = threadIdx.x;
  const int bid = blockIdx.x;
  const bool isBin = (bid % 3 == 2);

  if (!isBin) {
    // ================= gemm role: Wx = x @ W^T via MFMA, s_i/s_j fused =======
    const int gi = (bid / 3) * 2 + (bid % 3);   // 0..781, each exactly once
    unsigned short (*hs)[32][72] = reinterpret_cast<unsigned short(*)[32][72]>(smem);
    const int w = t >> 6;
    const int l = t & 63;
    const int lr = l & 15;
    const int lk = l >> 4;
    const int row0 = gi * 128 + w * 32;

    f32x4 acc[2][4];
    #pragma unroll
    for (int m = 0; m < 2; ++m)
      #pragma unroll
      for (int n = 0; n < 4; ++n) acc[m][n] = (f32x4){0.f, 0.f, 0.f, 0.f};

    #pragma unroll
    for (int ks = 0; ks < 4; ++ks) {
      const int k0 = ks * 32 + lk * 8;
      bf16x8 af[2], bfr[4];
      #pragma unroll
      for (int m = 0; m < 2; ++m) {
        int r = row0 + m * 16 + lr;
        r = (r < NN) ? r : (NN - 1);
        const float* p = &x[(size_t)r * INC + k0];
        float4 u0 = *reinterpret_cast<const float4*>(p);
        float4 u1 = *reinterpret_cast<const float4*>(p + 4);
        af[m][0] = (short)f2bf(u0.x); af[m][1] = (short)f2bf(u0.y);
        af[m][2] = (short)f2bf(u0.z); af[m][3] = (short)f2bf(u0.w);
        af[m][4] = (short)f2bf(u1.x); af[m][5] = (short)f2bf(u1.y);
        af[m][6] = (short)f2bf(u1.z); af[m][7] = (short)f2bf(u1.w);
      }
      #pragma unroll
      for (int n = 0; n < 4; ++n) {
        int c = n * 16 + lr;
        const float* p = &W[(size_t)c * INC + k0];
        float4 u0 = *reinterpret_cast<const float4*>(p);
        float4 u1 = *reinterpret_cast<const float4*>(p + 4);
        bfr[n][0] = (short)f2bf(u0.x); bfr[n][1] = (short)f2bf(u0.y);
        bfr[n][2] = (short)f2bf(u0.z); bfr[n][3] = (short)f2bf(u0.w);
        bfr[n][4] = (short)f2bf(u1.x); bfr[n][5] = (short)f2bf(u1.y);
        bfr[n][6] = (short)f2bf(u1.z); bfr[n][7] = (short)f2bf(u1.w);
      }
      #pragma unroll
      for (int m = 0; m < 2; ++m)
        #pragma unroll
        for (int n = 0; n < 4; ++n)
          acc[m][n] = __builtin_amdgcn_mfma_f32_16x16x32_bf16(af[m], bfr[n], acc[m][n], 0, 0, 0);
    }

    // fused score dots
    float a1[4], a2[4];
    #pragma unroll
    for (int n = 0; n < 4; ++n) {
      a1[n] = a[n * 16 + lr];
      a2[n] = a[OUTC + n * 16 + lr];
    }
    #pragma unroll
    for (int m = 0; m < 2; ++m)
      #pragma unroll
      for (int r = 0; r < 4; ++r) {
        float p1 = 0.f, p2 = 0.f;
        #pragma unroll
        for (int n = 0; n < 4; ++n) {
          p1 = fmaf(acc[m][n][r], a1[n], p1);
          p2 = fmaf(acc[m][n][r], a2[n], p2);
        }
        #pragma unroll
        for (int mm = 1; mm < 16; mm <<= 1) {
          p1 += __shfl_xor(p1, mm);
          p2 += __shfl_xor(p2, mm);
        }
        int rr = row0 + m * 16 + lk * 4 + r;
        if (lr == 0 && rr < NN) { s_i[rr] = p1; s_j[rr] = p2; }
      }

    // bf16 Wx store via per-wave LDS bounce -> coalesced uint4 stores
    #pragma unroll
    for (int m = 0; m < 2; ++m)
      #pragma unroll
      for (int n = 0; n < 4; ++n)
        #pragma unroll
        for (int r = 0; r < 4; ++r)
          hs[w][m * 16 + lk * 4 + r][n * 16 + lr] = f2bf(acc[m][n][r]);
    __syncthreads();
    #pragma unroll
    for (int j = 0; j < 4; ++j) {
      int idx = j * 64 + l;
      int rr = idx >> 3;
      int c8 = idx & 7;
      int node = row0 + rr;
      if (node < NN) {
        uint4 v = *reinterpret_cast<const uint4*>(&hs[w][rr][c8 * 8]);
        *reinterpret_cast<uint4*>(&Wxh[(size_t)node * OUTC + c8 * 8]) = v;
      }
    }
  } else {
    // ================= bin role: bucket-bin 4096 edges (burst writes) ========
    // Packed word: src (17b) | dl (7b) << 17. Rank-from-histogram.
    const int bi = bid / 3;                  // 0..390
    int* lh = reinterpret_cast<int*>(smem);                 // 1024 ints
    int* ls = lh + 1024;                                    // 1024 ints
    int* gb = ls + 1024;                                    // 784 ints
    uint2* stage = reinterpret_cast<uint2*>(smem + 11328);  // 4096 uint2 (8B-aligned)
    __shared__ int wsum[4];
    const int c0 = bi * CHUNKA;
    const int cend = min(c0 + CHUNKA, EE);
    const int total = cend - c0;

    #pragma unroll
    for (int k = 0; k < 4; ++k) lh[t + k * 256] = 0;
    __syncthreads();

    int esrc[16], edst[16], rnk[16];
    #pragma unroll
    for (int k = 0; k < 16; ++k) {
      int i = c0 + t + k * 256;
      bool v = i < cend;
      esrc[k] = v ? src[i] : -1;
      edst[k] = v ? dst[i] : -1;
      rnk[k] = v ? atomicAdd(&lh[edst[k] >> BSH], 1) : 0;
    }
    __syncthreads();

    // exclusive scan of 1024 cells: thread owns cells 4t..4t+3; wave shfl scan
    {
      int a0 = lh[4 * t], a1 = lh[4 * t + 1], a2 = lh[4 * t + 2], a3 = lh[4 * t + 3];
      int s4 = a0 + a1 + a2 + a3;
      int incl = s4;
      #pragma unroll
      for (int d = 1; d < 64; d <<= 1) {
        int u = __shfl_up(incl, d);
        if ((t & 63) >= d) incl += u;
      }
      if ((t & 63) == 63) wsum[t >> 6] = incl;
      __syncthreads();
      int wv = t >> 6;
      int wbase = 0;
      #pragma unroll
      for (int k = 0; k < 4; ++k) wbase += (k < wv) ? wsum[k] : 0;
      int ex = wbase + incl - s4;
      ls[4 * t] = ex;
      ls[4 * t + 1] = ex + a0;
      ls[4 * t + 2] = ex + a0 + a1;
      ls[4 * t + 3] = ex + a0 + a1 + a2;
    }
    __syncthreads();

    #pragma unroll
    for (int k = 0; k < 16; ++k) {
      if (edst[k] >= 0) {
        int bb = edst[k] >> BSH;
        stage[ls[bb] + rnk[k]] =
            make_uint2((unsigned)esrc[k] | ((unsigned)(edst[k] & (BNODES - 1)) << 17),
                       (unsigned)bb);
      }
    }
    __syncthreads();

    for (int b = t; b < NB; b += 256) {
      int cnt = lh[b];
      if (cnt) gb[b] = atomicAdd(&gcursor[b], cnt);
    }
    __syncthreads();

    // consecutive i -> same bucket -> coalesced full-line bursts
    for (int i = t; i < total; i += 256) {
      uint2 pr = stage[i];
      int b = (int)pr.y;
      int idx = gb[b] + (i - ls[b]);
      if (idx < BCAP) binned[b * BCAP + idx] = pr.x;   // clamp: never corrupt neighbors
    }
  }
}

// ---------------- K2: FUSED per-bucket sort + aggregate + ELU ------------------
// R20 lesson applied: dispatch-gap elimination is worth ~4-5us per boundary.
// Phase 1 (= old k_sort): rank-from-histogram scatter of packed (alpha|src)
// into LDS stage -- sorted4's 14MB write + 7MB read round-trip and offs2 are
// GONE. Phase 2: 2 threads/node (t>>1=node, t&1=channel half); each owns 32
// channels -> NO cross-lane reduce; per edge 4 independent 16B Wxh gathers,
// 2x-unrolled walk (8 loads in flight/lane). Phases are sequential (regalloc
// = max of phases, no R16 spill trap).
__global__ __launch_bounds__(256) void k_sa(const int* __restrict__ gcursor,
                                            const unsigned* __restrict__ binned,
                                            const float* __restrict__ s_i,
                                            const float* __restrict__ s_j,
                                            const unsigned short* __restrict__ Wxh,
                                            float* __restrict__ out) {
  __shared__ int cnt128[BNODES];
  __shared__ int ex128[BNODES];
  __shared__ float sil[BNODES];
  __shared__ float den[BNODES];
  __shared__ float invd[BNODES];
  __shared__ unsigned stage[BCAP];
  __shared__ int sW0;
  const int t = threadIdx.x;
  const int b = blockIdx.x;
  const int n0 = b << BSH;
  const int base = b * BCAP;
  const int cnt = min(gcursor[b], BCAP);

  if (t < BNODES) {
    cnt128[t] = 0;
    den[t] = 0.f;
    int n = n0 + t;
    sil[t] = (n < NN) ? s_i[n] : 0.f;
  }
  __syncthreads();

  // ---- phase 1: load + rank + weight + denom (register-staged) ----
  unsigned es[NSLOT];
  int ed[NSLOT], rk[NSLOT];
  float ws[NSLOT];
  #pragma unroll
  for (int k = 0; k < NSLOT; ++k) {
    int i = t + k * 256;
    bool v = i < cnt;
    unsigned pw = v ? binned[base + i] : 0u;
    es[k] = pw & 0x1ffffu;
    ed[k] = v ? (int)(pw >> 17) : -1;
    ws[k] = 0.f;
    rk[k] = 0;
    if (v) {
      rk[k] = atomicAdd(&cnt128[ed[k]], 1);
      float sc = sil[ed[k]] + s_j[es[k]];
      sc = (sc > 0.f) ? sc : NEG_SLOPE * sc;
      ws[k] = __expf(sc);
      atomicAdd(&den[ed[k]], ws[k]);
    }
  }
  __syncthreads();

  // inverse denom + exclusive scan of counts via 2-wave shfl scan
  int c0 = 0;
  if (t < BNODES) {
    float dv = den[t];
    invd[t] = (dv > 0.f) ? 1.f / dv : 0.f;
    c0 = cnt128[t];
  }
  int incl = c0;
  #pragma unroll
  for (int d = 1; d < 64; d <<= 1) {
    int u = __shfl_up(incl, d);
    if ((t & 63) >= d) incl += u;
  }
  if (t == 63) sW0 = incl;
  __syncthreads();
  if (t < BNODES) ex128[t] = incl - c0 + ((t >= 64) ? sW0 : 0);
  __syncthreads();

  // scatter packed (alpha_hi15 | src) into node-sorted LDS order
  #pragma unroll
  for (int k = 0; k < NSLOT; ++k) {
    if (ed[k] >= 0) {
      float alpha = ws[k] * invd[ed[k]];
      unsigned abits = (__float_as_uint(alpha) + 0x10000u) & 0xfffe0000u;  // RNE to 15b
      stage[ex128[ed[k]] + rk[k]] = abits | es[k];
    }
  }
  __syncthreads();

  // ---- phase 2: per-node aggregation straight from LDS ----
  const int dl = t >> 1;             // node within bucket
  const unsigned cb = (t & 1) << 5;  // channel half base: 0 or 32
  const int myCnt = cnt128[dl];
  const int myEx = ex128[dl];
  float acc[32];
  #pragma unroll
  for (int j = 0; j < 32; ++j) acc[j] = 0.f;

  #define EDGE_BODY(E) do {                                              \
    unsigned u = stage[myEx + (E)];                                      \
    float wgt = __uint_as_float(u & 0xfffe0000u);                        \
    const uint4* hp = reinterpret_cast<const uint4*>(&Wxh[((u & 0x1ffffu) << 6) + cb]); \
    uint4 h0 = hp[0], h1 = hp[1], h2 = hp[2], h3 = hp[3];                \
    acc[0]  = fmaf(wgt, bf2f(h0.x & 0xffffu), acc[0]);                   \
    acc[1]  = fmaf(wgt, bf2f(h0.x >> 16), acc[1]);                       \
    acc[2]  = fmaf(wgt, bf2f(h0.y & 0xffffu), acc[2]);                   \
    acc[3]  = fmaf(wgt, bf2f(h0.y >> 16), acc[3]);                       \
    acc[4]  = fmaf(wgt, bf2f(h0.z & 0xffffu), acc[4]);                   \
    acc[5]  = fmaf(wgt, bf2f(h0.z >> 16), acc[5]);                       \
    acc[6]  = fmaf(wgt, bf2f(h0.w & 0xffffu), acc[6]);                   \
    acc[7]  = fmaf(wgt, bf2f(h0.w >> 16), acc[7]);                       \
    acc[8]  = fmaf(wgt, bf2f(h1.x & 0xffffu), acc[8]);                   \
    acc[9]  = fmaf(wgt, bf2f(h1.x >> 16), acc[9]);                       \
    acc[10] = fmaf(wgt, bf2f(h1.y & 0xffffu), acc[10]);                  \
    acc[11] = fmaf(wgt, bf2f(h1.y >> 16), acc[11]);                      \
    acc[12] = fmaf(wgt, bf2f(h1.z & 0xffffu), acc[12]);                  \
    acc[13] = fmaf(wgt, bf2f(h1.z >> 16), acc[13]);                      \
    acc[14] = fmaf(wgt, bf2f(h1.w & 0xffffu), acc[14]);                  \
    acc[15] = fmaf(wgt, bf2f(h1.w >> 16), acc[15]);                      \
    acc[16] = fmaf(wgt, bf2f(h2.x & 0xffffu), acc[16]);                  \
    acc[17] = fmaf(wgt, bf2f(h2.x >> 16), acc[17]);                      \
    acc[18] = fmaf(wgt, bf2f(h2.y & 0xffffu), acc[18]);                  \
    acc[19] = fmaf(wgt, bf2f(h2.y >> 16), acc[19]);                      \
    acc[20] = fmaf(wgt, bf2f(h2.z & 0xffffu), acc[20]);                  \
    acc[21] = fmaf(wgt, bf2f(h2.z >> 16), acc[21]);                      \
    acc[22] = fmaf(wgt, bf2f(h2.w & 0xffffu), acc[22]);                  \
    acc[23] = fmaf(wgt, bf2f(h2.w >> 16), acc[23]);                      \
    acc[24] = fmaf(wgt, bf2f(h3.x & 0xffffu), acc[24]);                  \
    acc[25] = fmaf(wgt, bf2f(h3.x >> 16), acc[25]);                      \
    acc[26] = fmaf(wgt, bf2f(h3.y & 0xffffu), acc[26]);                  \
    acc[27] = fmaf(wgt, bf2f(h3.y >> 16), acc[27]);                      \
    acc[28] = fmaf(wgt, bf2f(h3.z & 0xffffu), acc[28]);                  \
    acc[29] = fmaf(wgt, bf2f(h3.z >> 16), acc[29]);                      \
    acc[30] = fmaf(wgt, bf2f(h3.w & 0xffffu), acc[30]);                  \
    acc[31] = fmaf(wgt, bf2f(h3.w >> 16), acc[31]);                      \
  } while (0)

  int e = 0;
  for (; e + 2 <= myCnt; e += 2) { EDGE_BODY(e); EDGE_BODY(e + 1); }
  if (e < myCnt) EDGE_BODY(e);
  #undef EDGE_BODY

  const int n = n0 + dl;
  if (n < NN) {
    unsigned ob = ((unsigned)n << 6) + cb;
    #pragma unroll
    for (int q = 0; q < 8; ++q) {
      float4 r;
      #pragma unroll
      for (int j = 0; j < 4; ++j) {
        float v = acc[q * 4 + j];
        (&r.x)[j] = (v > 0.f) ? v : __expf(v) - 1.f;   // elu
      }
      *reinterpret_cast<float4*>(&out[ob + q * 4]) = r;
    }
  }
}

extern "C" void kernel_launch(void* const* d_in, const int* in_sizes, int n_in,
                              void* d_out, int out_size, void* d_ws, size_t ws_size,
                              hipStream_t stream) {
  const float* x = (const float*)d_in[0];
  const int* edge = (const int*)d_in[1];   // [2, E]: row 0 = src, row 1 = dst
  const float* W = (const float*)d_in[2];
  const float* a = (const float*)d_in[3];
  const int* srcIdx = edge;
  const int* dstIdx = edge + EE;
  float* out = (float*)d_out;

  // workspace layout (~22 MB): sorted4 + offs2 eliminated by the k_sa fusion.
  unsigned short* Wxh = (unsigned short*)d_ws;                     // N*64 bf16 = 12.8 MB
  unsigned* binned = (unsigned*)((char*)d_ws + (size_t)NN * OUTC * 2);  // NB*BCAP*4B = 8.0 MB
  int* gcursor = (int*)(binned + (size_t)NB * BCAP);               // NB
  float* s_i = (float*)(gcursor + NB);                             // N
  float* s_j = s_i + NN;                                           // N

  k_zero<<<1, 256, 0, stream>>>(gcursor);
  k_gb<<<NBLKG, 256, 0, stream>>>(x, W, a, Wxh, s_i, s_j, srcIdx, dstIdx, gcursor, binned);
  k_sa<<<NB, 256, 0, stream>>>(gcursor, binned, s_i, s_j, Wxh, out);
}

// Round 22
// 89.846 us; speedup vs baseline: 1.2054x; 1.0213x over previous
//
#include <hip/hip_runtime.h>

#define NN 100000
#define EE 1600000
#define INC 128
#define OUTC 64
#define NEG_SLOPE 0.2f

#define BSH 7                 // bucket = dst >> 7 (128 nodes/bucket)
#define BNODES 128
#define NB 782                // ceil(NN/128)
#define BCAP 2560             // padded bucket capacity (mean 2048, +11 sigma)
#define CHUNKA 4096           // edges per bin-role block (256 threads x 16)
#define NBLKA 391             // ceil(EE/CHUNKA)
#define NBLKG (NB + NBLKA)    // merged grid: 782 gemm + 391 bin = 1173
#define NSLOT 10              // k_sa sort-phase register slots: 10*256 = 2560 = BCAP

typedef __attribute__((ext_vector_type(8))) short bf16x8;
typedef __attribute__((ext_vector_type(4))) float f32x4;

__device__ __forceinline__ unsigned short f2bf(float f) {
  unsigned u = __float_as_uint(f);
  unsigned r = (u + 0x7fffu + ((u >> 16) & 1u)) >> 16;  // RNE
  return (unsigned short)r;
}
__device__ __forceinline__ float bf2f(unsigned u16) {
  return __uint_as_float(u16 << 16);
}

// ---------------- K0: zero bucket cursors (must precede k_gb's bin role) -------
__global__ __launch_bounds__(256) void k_zero(int* __restrict__ gcursor) {
  for (int i = threadIdx.x; i < NB; i += 256) gcursor[i] = 0;
}

// ---------------- K1: gemm-role || bin-role, INTERLEAVED (unchanged from R20) --
__global__ __launch_bounds__(256)
__attribute__((amdgpu_waves_per_eu(1, 3)))
void k_gb(
    const float* __restrict__ x, const float* __restrict__ W,
    const float* __restrict__ a, unsigned short* __restrict__ Wxh,
    float* __restrict__ s_i, float* __restrict__ s_j,
    const int* __restrict__ src, const int* __restrict__ dst,
    int* __restrict__ gcursor, unsigned* __restrict__ binned)
{
  __shared__ __align__(16) char smem[44240];   // union: gemm 18.4KB | bin 43.2KB
  const int t = threadIdx.x;
  const int bid = blockIdx.x;
  const bool isBin = (bid % 3 == 2);

  if (!isBin) {
    // ================= gemm role: Wx = x @ W^T via MFMA, s_i/s_j fused =======
    const int gi = (bid / 3) * 2 + (bid % 3);   // 0..781, each exactly once
    unsigned short (*hs)[32][72] = reinterpret_cast<unsigned short(*)[32][72]>(smem);
    const int w = t >> 6;
    const int l = t & 63;
    const int lr = l & 15;
    const int lk = l >> 4;
    const int row0 = gi * 128 + w * 32;

    f32x4 acc[2][4];
    #pragma unroll
    for (int m = 0; m < 2; ++m)
      #pragma unroll
      for (int n = 0; n < 4; ++n) acc[m][n] = (f32x4){0.f, 0.f, 0.f, 0.f};

    #pragma unroll
    for (int ks = 0; ks < 4; ++ks) {
      const int k0 = ks * 32 + lk * 8;
      bf16x8 af[2], bfr[4];
      #pragma unroll
      for (int m = 0; m < 2; ++m) {
        int r = row0 + m * 16 + lr;
        r = (r < NN) ? r : (NN - 1);
        const float* p = &x[(size_t)r * INC + k0];
        float4 u0 = *reinterpret_cast<const float4*>(p);
        float4 u1 = *reinterpret_cast<const float4*>(p + 4);
        af[m][0] = (short)f2bf(u0.x); af[m][1] = (short)f2bf(u0.y);
        af[m][2] = (short)f2bf(u0.z); af[m][3] = (short)f2bf(u0.w);
        af[m][4] = (short)f2bf(u1.x); af[m][5] = (short)f2bf(u1.y);
        af[m][6] = (short)f2bf(u1.z); af[m][7] = (short)f2bf(u1.w);
      }
      #pragma unroll
      for (int n = 0; n < 4; ++n) {
        int c = n * 16 + lr;
        const float* p = &W[(size_t)c * INC + k0];
        float4 u0 = *reinterpret_cast<const float4*>(p);
        float4 u1 = *reinterpret_cast<const float4*>(p + 4);
        bfr[n][0] = (short)f2bf(u0.x); bfr[n][1] = (short)f2bf(u0.y);
        bfr[n][2] = (short)f2bf(u0.z); bfr[n][3] = (short)f2bf(u0.w);
        bfr[n][4] = (short)f2bf(u1.x); bfr[n][5] = (short)f2bf(u1.y);
        bfr[n][6] = (short)f2bf(u1.z); bfr[n][7] = (short)f2bf(u1.w);
      }
      #pragma unroll
      for (int m = 0; m < 2; ++m)
        #pragma unroll
        for (int n = 0; n < 4; ++n)
          acc[m][n] = __builtin_amdgcn_mfma_f32_16x16x32_bf16(af[m], bfr[n], acc[m][n], 0, 0, 0);
    }

    // fused score dots
    float a1[4], a2[4];
    #pragma unroll
    for (int n = 0; n < 4; ++n) {
      a1[n] = a[n * 16 + lr];
      a2[n] = a[OUTC + n * 16 + lr];
    }
    #pragma unroll
    for (int m = 0; m < 2; ++m)
      #pragma unroll
      for (int r = 0; r < 4; ++r) {
        float p1 = 0.f, p2 = 0.f;
        #pragma unroll
        for (int n = 0; n < 4; ++n) {
          p1 = fmaf(acc[m][n][r], a1[n], p1);
          p2 = fmaf(acc[m][n][r], a2[n], p2);
        }
        #pragma unroll
        for (int mm = 1; mm < 16; mm <<= 1) {
          p1 += __shfl_xor(p1, mm);
          p2 += __shfl_xor(p2, mm);
        }
        int rr = row0 + m * 16 + lk * 4 + r;
        if (lr == 0 && rr < NN) { s_i[rr] = p1; s_j[rr] = p2; }
      }

    // bf16 Wx store via per-wave LDS bounce -> coalesced uint4 stores
    #pragma unroll
    for (int m = 0; m < 2; ++m)
      #pragma unroll
      for (int n = 0; n < 4; ++n)
        #pragma unroll
        for (int r = 0; r < 4; ++r)
          hs[w][m * 16 + lk * 4 + r][n * 16 + lr] = f2bf(acc[m][n][r]);
    __syncthreads();
    #pragma unroll
    for (int j = 0; j < 4; ++j) {
      int idx = j * 64 + l;
      int rr = idx >> 3;
      int c8 = idx & 7;
      int node = row0 + rr;
      if (node < NN) {
        uint4 v = *reinterpret_cast<const uint4*>(&hs[w][rr][c8 * 8]);
        *reinterpret_cast<uint4*>(&Wxh[(size_t)node * OUTC + c8 * 8]) = v;
      }
    }
  } else {
    // ================= bin role: bucket-bin 4096 edges (burst writes) ========
    const int bi = bid / 3;                  // 0..390
    int* lh = reinterpret_cast<int*>(smem);                 // 1024 ints
    int* ls = lh + 1024;                                    // 1024 ints
    int* gb = ls + 1024;                                    // 784 ints
    uint2* stage = reinterpret_cast<uint2*>(smem + 11328);  // 4096 uint2
    __shared__ int wsum[4];
    const int c0 = bi * CHUNKA;
    const int cend = min(c0 + CHUNKA, EE);
    const int total = cend - c0;

    #pragma unroll
    for (int k = 0; k < 4; ++k) lh[t + k * 256] = 0;
    __syncthreads();

    int esrc[16], edst[16], rnk[16];
    #pragma unroll
    for (int k = 0; k < 16; ++k) {
      int i = c0 + t + k * 256;
      bool v = i < cend;
      esrc[k] = v ? src[i] : -1;
      edst[k] = v ? dst[i] : -1;
      rnk[k] = v ? atomicAdd(&lh[edst[k] >> BSH], 1) : 0;
    }
    __syncthreads();

    // exclusive scan of 1024 cells: thread owns cells 4t..4t+3; wave shfl scan
    {
      int a0 = lh[4 * t], a1 = lh[4 * t + 1], a2 = lh[4 * t + 2], a3 = lh[4 * t + 3];
      int s4 = a0 + a1 + a2 + a3;
      int incl = s4;
      #pragma unroll
      for (int d = 1; d < 64; d <<= 1) {
        int u = __shfl_up(incl, d);
        if ((t & 63) >= d) incl += u;
      }
      if ((t & 63) == 63) wsum[t >> 6] = incl;
      __syncthreads();
      int wv = t >> 6;
      int wbase = 0;
      #pragma unroll
      for (int k = 0; k < 4; ++k) wbase += (k < wv) ? wsum[k] : 0;
      int ex = wbase + incl - s4;
      ls[4 * t] = ex;
      ls[4 * t + 1] = ex + a0;
      ls[4 * t + 2] = ex + a0 + a1;
      ls[4 * t + 3] = ex + a0 + a1 + a2;
    }
    __syncthreads();

    #pragma unroll
    for (int k = 0; k < 16; ++k) {
      if (edst[k] >= 0) {
        int bb = edst[k] >> BSH;
        stage[ls[bb] + rnk[k]] =
            make_uint2((unsigned)esrc[k] | ((unsigned)(edst[k] & (BNODES - 1)) << 17),
                       (unsigned)bb);
      }
    }
    __syncthreads();

    for (int b = t; b < NB; b += 256) {
      int cnt = lh[b];
      if (cnt) gb[b] = atomicAdd(&gcursor[b], cnt);
    }
    __syncthreads();

    // consecutive i -> same bucket -> coalesced full-line bursts
    for (int i = t; i < total; i += 256) {
      uint2 pr = stage[i];
      int b = (int)pr.y;
      int idx = gb[b] + (i - ls[b]);
      if (idx < BCAP) binned[b * BCAP + idx] = pr.x;   // clamp: never corrupt neighbors
    }
  }
}

// ---------------- K2: FUSED per-bucket sort + aggregate + ELU ------------------
// Phase 1: rank-from-histogram scatter of packed (alpha|src) into LDS stage.
// Phase 2 REWORKED (R21 lesson: 2-thread/node serial walk -> block waits on
// max-degree node): k_aggregate's proven geometry reading LDS -- 8 half-waves
// x 16 rounds; each 32-lane half does one node/round with 4 quad-groups x 4
// edges in flight (lane = 8 channels), shfl_xor(8,16) reduce. Imbalance
// amortizes over 16 nodes/half; 16 gathers in flight per half.
__global__ __launch_bounds__(256) void k_sa(const int* __restrict__ gcursor,
                                            const unsigned* __restrict__ binned,
                                            const float* __restrict__ s_i,
                                            const float* __restrict__ s_j,
                                            const unsigned short* __restrict__ Wxh,
                                            float* __restrict__ out) {
  __shared__ int cnt128[BNODES];
  __shared__ int ex128[BNODES];
  __shared__ float sil[BNODES];
  __shared__ float den[BNODES];
  __shared__ float invd[BNODES];
  __shared__ unsigned stage[BCAP];
  __shared__ int sW0;
  const int t = threadIdx.x;
  const int b = blockIdx.x;
  const int n0 = b << BSH;
  const int base = b * BCAP;
  const int cnt = min(gcursor[b], BCAP);

  if (t < BNODES) {
    cnt128[t] = 0;
    den[t] = 0.f;
    int n = n0 + t;
    sil[t] = (n < NN) ? s_i[n] : 0.f;
  }
  __syncthreads();

  // ---- phase 1: load + rank + weight + denom (register-staged) ----
  unsigned es[NSLOT];
  int ed[NSLOT], rk[NSLOT];
  float ws[NSLOT];
  #pragma unroll
  for (int k = 0; k < NSLOT; ++k) {
    int i = t + k * 256;
    bool v = i < cnt;
    unsigned pw = v ? binned[base + i] : 0u;
    es[k] = pw & 0x1ffffu;
    ed[k] = v ? (int)(pw >> 17) : -1;
    ws[k] = 0.f;
    rk[k] = 0;
    if (v) {
      rk[k] = atomicAdd(&cnt128[ed[k]], 1);
      float sc = sil[ed[k]] + s_j[es[k]];
      sc = (sc > 0.f) ? sc : NEG_SLOPE * sc;
      ws[k] = __expf(sc);
      atomicAdd(&den[ed[k]], ws[k]);
    }
  }
  __syncthreads();

  // inverse denom + exclusive scan of counts via 2-wave shfl scan
  int c0 = 0;
  if (t < BNODES) {
    float dv = den[t];
    invd[t] = (dv > 0.f) ? 1.f / dv : 0.f;
    c0 = cnt128[t];
  }
  int incl = c0;
  #pragma unroll
  for (int d = 1; d < 64; d <<= 1) {
    int u = __shfl_up(incl, d);
    if ((t & 63) >= d) incl += u;
  }
  if (t == 63) sW0 = incl;
  __syncthreads();
  if (t < BNODES) ex128[t] = incl - c0 + ((t >= 64) ? sW0 : 0);
  __syncthreads();

  // scatter packed (alpha_hi15 | src) into node-sorted LDS order
  #pragma unroll
  for (int k = 0; k < NSLOT; ++k) {
    if (ed[k] >= 0) {
      float alpha = ws[k] * invd[ed[k]];
      unsigned abits = (__float_as_uint(alpha) + 0x10000u) & 0xfffe0000u;  // RNE to 15b
      stage[ex128[ed[k]] + rk[k]] = abits | es[k];
    }
  }
  __syncthreads();

  // ---- phase 2: half-wave per node, 4 edges x 4 quads in flight ----
  const int half = t >> 5;           // 0..7
  const int l32 = t & 31;
  const int g = l32 >> 3;            // quad slot 0..3
  const unsigned cl8 = (l32 & 7) << 3;  // channel octet base

  for (int rnd = 0; rnd < 16; ++rnd) {
    const int dl = rnd * 8 + half;
    const int myCnt = cnt128[dl];
    const int myEx = ex128[dl];
    float acc[8];
    #pragma unroll
    for (int j = 0; j < 8; ++j) acc[j] = 0.f;

    for (int eb = 0; eb < myCnt; eb += 16) {
      int i0 = eb + 4 * g;
      unsigned u0 = (i0 + 0 < myCnt) ? stage[myEx + i0 + 0] : 0u;
      unsigned u1 = (i0 + 1 < myCnt) ? stage[myEx + i0 + 1] : 0u;
      unsigned u2 = (i0 + 2 < myCnt) ? stage[myEx + i0 + 2] : 0u;
      unsigned u3 = (i0 + 3 < myCnt) ? stage[myEx + i0 + 3] : 0u;
      float w0 = __uint_as_float(u0 & 0xfffe0000u);   // pads: +0.0, src 0 (safe)
      float w1 = __uint_as_float(u1 & 0xfffe0000u);
      float w2 = __uint_as_float(u2 & 0xfffe0000u);
      float w3 = __uint_as_float(u3 & 0xfffe0000u);
      uint4 h0 = *reinterpret_cast<const uint4*>(&Wxh[((u0 & 0x1ffffu) << 6) + cl8]);
      uint4 h1 = *reinterpret_cast<const uint4*>(&Wxh[((u1 & 0x1ffffu) << 6) + cl8]);
      uint4 h2 = *reinterpret_cast<const uint4*>(&Wxh[((u2 & 0x1ffffu) << 6) + cl8]);
      uint4 h3 = *reinterpret_cast<const uint4*>(&Wxh[((u3 & 0x1ffffu) << 6) + cl8]);
      acc[0] = fmaf(w0, bf2f(h0.x & 0xffffu), acc[0]);
      acc[1] = fmaf(w0, bf2f(h0.x >> 16), acc[1]);
      acc[2] = fmaf(w0, bf2f(h0.y & 0xffffu), acc[2]);
      acc[3] = fmaf(w0, bf2f(h0.y >> 16), acc[3]);
      acc[4] = fmaf(w0, bf2f(h0.z & 0xffffu), acc[4]);
      acc[5] = fmaf(w0, bf2f(h0.z >> 16), acc[5]);
      acc[6] = fmaf(w0, bf2f(h0.w & 0xffffu), acc[6]);
      acc[7] = fmaf(w0, bf2f(h0.w >> 16), acc[7]);
      acc[0] = fmaf(w1, bf2f(h1.x & 0xffffu), acc[0]);
      acc[1] = fmaf(w1, bf2f(h1.x >> 16), acc[1]);
      acc[2] = fmaf(w1, bf2f(h1.y & 0xffffu), acc[2]);
      acc[3] = fmaf(w1, bf2f(h1.y >> 16), acc[3]);
      acc[4] = fmaf(w1, bf2f(h1.z & 0xffffu), acc[4]);
      acc[5] = fmaf(w1, bf2f(h1.z >> 16), acc[5]);
      acc[6] = fmaf(w1, bf2f(h1.w & 0xffffu), acc[6]);
      acc[7] = fmaf(w1, bf2f(h1.w >> 16), acc[7]);
      acc[0] = fmaf(w2, bf2f(h2.x & 0xffffu), acc[0]);
      acc[1] = fmaf(w2, bf2f(h2.x >> 16), acc[1]);
      acc[2] = fmaf(w2, bf2f(h2.y & 0xffffu), acc[2]);
      acc[3] = fmaf(w2, bf2f(h2.y >> 16), acc[3]);
      acc[4] = fmaf(w2, bf2f(h2.z & 0xffffu), acc[4]);
      acc[5] = fmaf(w2, bf2f(h2.z >> 16), acc[5]);
      acc[6] = fmaf(w2, bf2f(h2.w & 0xffffu), acc[6]);
      acc[7] = fmaf(w2, bf2f(h2.w >> 16), acc[7]);
      acc[0] = fmaf(w3, bf2f(h3.x & 0xffffu), acc[0]);
      acc[1] = fmaf(w3, bf2f(h3.x >> 16), acc[1]);
      acc[2] = fmaf(w3, bf2f(h3.y & 0xffffu), acc[2]);
      acc[3] = fmaf(w3, bf2f(h3.y >> 16), acc[3]);
      acc[4] = fmaf(w3, bf2f(h3.z & 0xffffu), acc[4]);
      acc[5] = fmaf(w3, bf2f(h3.z >> 16), acc[5]);
      acc[6] = fmaf(w3, bf2f(h3.w & 0xffffu), acc[6]);
      acc[7] = fmaf(w3, bf2f(h3.w >> 16), acc[7]);
    }

    #pragma unroll
    for (int m = 8; m <= 16; m <<= 1) {
      #pragma unroll
      for (int j = 0; j < 8; ++j) acc[j] += __shfl_xor(acc[j], m);
    }

    const int n = n0 + dl;
    if (g == 0 && n < NN) {
      float r[8];
      #pragma unroll
      for (int j = 0; j < 8; ++j)
        r[j] = (acc[j] > 0.f) ? acc[j] : __expf(acc[j]) - 1.f;   // elu
      unsigned ob = ((unsigned)n << 6) + cl8;
      *reinterpret_cast<float4*>(&out[ob]) = make_float4(r[0], r[1], r[2], r[3]);
      *reinterpret_cast<float4*>(&out[ob + 4]) = make_float4(r[4], r[5], r[6], r[7]);
    }
  }
}

extern "C" void kernel_launch(void* const* d_in, const int* in_sizes, int n_in,
                              void* d_out, int out_size, void* d_ws, size_t ws_size,
                              hipStream_t stream) {
  const float* x = (const float*)d_in[0];
  const int* edge = (const int*)d_in[1];   // [2, E]: row 0 = src, row 1 = dst
  const float* W = (const float*)d_in[2];
  const float* a = (const float*)d_in[3];
  const int* srcIdx = edge;
  const int* dstIdx = edge + EE;
  float* out = (float*)d_out;

  // workspace layout (~22 MB): sorted4 + offs2 eliminated by the k_sa fusion.
  unsigned short* Wxh = (unsigned short*)d_ws;                     // N*64 bf16 = 12.8 MB
  unsigned* binned = (unsigned*)((char*)d_ws + (size_t)NN * OUTC * 2);  // NB*BCAP*4B = 8.0 MB
  int* gcursor = (int*)(binned + (size_t)NB * BCAP);               // NB
  float* s_i = (float*)(gcursor + NB);                             // N
  float* s_j = s_i + NN;                                           // N

  k_zero<<<1, 256, 0, stream>>>(gcursor);
  k_gb<<<NBLKG, 256, 0, stream>>>(x, W, a, Wxh, s_i, s_j, srcIdx, dstIdx, gcursor, binned);
  k_sa<<<NB, 256, 0, stream>>>(gcursor, binned, s_i, s_j, Wxh, out);
}

// Round 23
// 89.381 us; speedup vs baseline: 1.2117x; 1.0052x over previous
//
#include <hip/hip_runtime.h>

#define NN 100000
#define EE 1600000
#define INC 128
#define OUTC 64
#define NEG_SLOPE 0.2f

#define BSH 7                 // bucket = dst >> 7 (128 nodes/bucket)
#define BNODES 128
#define NB 782                // ceil(NN/128)
#define BCAP 2560             // padded bucket capacity (mean 2048, +11 sigma)
#define CHUNKA 4096           // edges per bin-role block (256 threads x 16)
#define NBLKA 391             // ceil(EE/CHUNKA)
#define NBLKG (NB + NBLKA)    // merged grid: 782 gemm + 391 bin = 1173
#define NSLOT 5               // k_sa sort-phase register slots: 5*512 = 2560 = BCAP

typedef __attribute__((ext_vector_type(8))) short bf16x8;
typedef __attribute__((ext_vector_type(4))) float f32x4;

__device__ __forceinline__ unsigned short f2bf(float f) {
  unsigned u = __float_as_uint(f);
  unsigned r = (u + 0x7fffu + ((u >> 16) & 1u)) >> 16;  // RNE
  return (unsigned short)r;
}
__device__ __forceinline__ float bf2f(unsigned u16) {
  return __uint_as_float(u16 << 16);
}

// ---------------- K0: zero bucket cursors (must precede k_gb's bin role) -------
__global__ __launch_bounds__(256) void k_zero(int* __restrict__ gcursor) {
  for (int i = threadIdx.x; i < NB; i += 256) gcursor[i] = 0;
}

// ---------------- K1: gemm-role || bin-role, INTERLEAVED (unchanged from R20) --
__global__ __launch_bounds__(256)
__attribute__((amdgpu_waves_per_eu(1, 3)))
void k_gb(
    const float* __restrict__ x, const float* __restrict__ W,
    const float* __restrict__ a, unsigned short* __restrict__ Wxh,
    float* __restrict__ s_i, float* __restrict__ s_j,
    const int* __restrict__ src, const int* __restrict__ dst,
    int* __restrict__ gcursor, unsigned* __restrict__ binned)
{
  __shared__ __align__(16) char smem[44240];   // union: gemm 18.4KB | bin 43.2KB
  const int t = threadIdx.x;
  const int bid = blockIdx.x;
  const bool isBin = (bid % 3 == 2);

  if (!isBin) {
    // ================= gemm role: Wx = x @ W^T via MFMA, s_i/s_j fused =======
    const int gi = (bid / 3) * 2 + (bid % 3);   // 0..781, each exactly once
    unsigned short (*hs)[32][72] = reinterpret_cast<unsigned short(*)[32][72]>(smem);
    const int w = t >> 6;
    const int l = t & 63;
    const int lr = l & 15;
    const int lk = l >> 4;
    const int row0 = gi * 128 + w * 32;

    f32x4 acc[2][4];
    #pragma unroll
    for (int m = 0; m < 2; ++m)
      #pragma unroll
      for (int n = 0; n < 4; ++n) acc[m][n] = (f32x4){0.f, 0.f, 0.f, 0.f};

    #pragma unroll
    for (int ks = 0; ks < 4; ++ks) {
      const int k0 = ks * 32 + lk * 8;
      bf16x8 af[2], bfr[4];
      #pragma unroll
      for (int m = 0; m < 2; ++m) {
        int r = row0 + m * 16 + lr;
        r = (r < NN) ? r : (NN - 1);
        const float* p = &x[(size_t)r * INC + k0];
        float4 u0 = *reinterpret_cast<const float4*>(p);
        float4 u1 = *reinterpret_cast<const float4*>(p + 4);
        af[m][0] = (short)f2bf(u0.x); af[m][1] = (short)f2bf(u0.y);
        af[m][2] = (short)f2bf(u0.z); af[m][3] = (short)f2bf(u0.w);
        af[m][4] = (short)f2bf(u1.x); af[m][5] = (short)f2bf(u1.y);
        af[m][6] = (short)f2bf(u1.z); af[m][7] = (short)f2bf(u1.w);
      }
      #pragma unroll
      for (int n = 0; n < 4; ++n) {
        int c = n * 16 + lr;
        const float* p = &W[(size_t)c * INC + k0];
        float4 u0 = *reinterpret_cast<const float4*>(p);
        float4 u1 = *reinterpret_cast<const float4*>(p + 4);
        bfr[n][0] = (short)f2bf(u0.x); bfr[n][1] = (short)f2bf(u0.y);
        bfr[n][2] = (short)f2bf(u0.z); bfr[n][3] = (short)f2bf(u0.w);
        bfr[n][4] = (short)f2bf(u1.x); bfr[n][5] = (short)f2bf(u1.y);
        bfr[n][6] = (short)f2bf(u1.z); bfr[n][7] = (short)f2bf(u1.w);
      }
      #pragma unroll
      for (int m = 0; m < 2; ++m)
        #pragma unroll
        for (int n = 0; n < 4; ++n)
          acc[m][n] = __builtin_amdgcn_mfma_f32_16x16x32_bf16(af[m], bfr[n], acc[m][n], 0, 0, 0);
    }

    // fused score dots
    float a1[4], a2[4];
    #pragma unroll
    for (int n = 0; n < 4; ++n) {
      a1[n] = a[n * 16 + lr];
      a2[n] = a[OUTC + n * 16 + lr];
    }
    #pragma unroll
    for (int m = 0; m < 2; ++m)
      #pragma unroll
      for (int r = 0; r < 4; ++r) {
        float p1 = 0.f, p2 = 0.f;
        #pragma unroll
        for (int n = 0; n < 4; ++n) {
          p1 = fmaf(acc[m][n][r], a1[n], p1);
          p2 = fmaf(acc[m][n][r], a2[n], p2);
        }
        #pragma unroll
        for (int mm = 1; mm < 16; mm <<= 1) {
          p1 += __shfl_xor(p1, mm);
          p2 += __shfl_xor(p2, mm);
        }
        int rr = row0 + m * 16 + lk * 4 + r;
        if (lr == 0 && rr < NN) { s_i[rr] = p1; s_j[rr] = p2; }
      }

    // bf16 Wx store via per-wave LDS bounce -> coalesced uint4 stores
    #pragma unroll
    for (int m = 0; m < 2; ++m)
      #pragma unroll
      for (int n = 0; n < 4; ++n)
        #pragma unroll
        for (int r = 0; r < 4; ++r)
          hs[w][m * 16 + lk * 4 + r][n * 16 + lr] = f2bf(acc[m][n][r]);
    __syncthreads();
    #pragma unroll
    for (int j = 0; j < 4; ++j) {
      int idx = j * 64 + l;
      int rr = idx >> 3;
      int c8 = idx & 7;
      int node = row0 + rr;
      if (node < NN) {
        uint4 v = *reinterpret_cast<const uint4*>(&hs[w][rr][c8 * 8]);
        *reinterpret_cast<uint4*>(&Wxh[(size_t)node * OUTC + c8 * 8]) = v;
      }
    }
  } else {
    // ================= bin role: bucket-bin 4096 edges (burst writes) ========
    const int bi = bid / 3;                  // 0..390
    int* lh = reinterpret_cast<int*>(smem);                 // 1024 ints
    int* ls = lh + 1024;                                    // 1024 ints
    int* gb = ls + 1024;                                    // 784 ints
    uint2* stage = reinterpret_cast<uint2*>(smem + 11328);  // 4096 uint2
    __shared__ int wsum[4];
    const int c0 = bi * CHUNKA;
    const int cend = min(c0 + CHUNKA, EE);
    const int total = cend - c0;

    #pragma unroll
    for (int k = 0; k < 4; ++k) lh[t + k * 256] = 0;
    __syncthreads();

    int esrc[16], edst[16], rnk[16];
    #pragma unroll
    for (int k = 0; k < 16; ++k) {
      int i = c0 + t + k * 256;
      bool v = i < cend;
      esrc[k] = v ? src[i] : -1;
      edst[k] = v ? dst[i] : -1;
      rnk[k] = v ? atomicAdd(&lh[edst[k] >> BSH], 1) : 0;
    }
    __syncthreads();

    // exclusive scan of 1024 cells: thread owns cells 4t..4t+3; wave shfl scan
    {
      int a0 = lh[4 * t], a1 = lh[4 * t + 1], a2 = lh[4 * t + 2], a3 = lh[4 * t + 3];
      int s4 = a0 + a1 + a2 + a3;
      int incl = s4;
      #pragma unroll
      for (int d = 1; d < 64; d <<= 1) {
        int u = __shfl_up(incl, d);
        if ((t & 63) >= d) incl += u;
      }
      if ((t & 63) == 63) wsum[t >> 6] = incl;
      __syncthreads();
      int wv = t >> 6;
      int wbase = 0;
      #pragma unroll
      for (int k = 0; k < 4; ++k) wbase += (k < wv) ? wsum[k] : 0;
      int ex = wbase + incl - s4;
      ls[4 * t] = ex;
      ls[4 * t + 1] = ex + a0;
      ls[4 * t + 2] = ex + a0 + a1;
      ls[4 * t + 3] = ex + a0 + a1 + a2;
    }
    __syncthreads();

    #pragma unroll
    for (int k = 0; k < 16; ++k) {
      if (edst[k] >= 0) {
        int bb = edst[k] >> BSH;
        stage[ls[bb] + rnk[k]] =
            make_uint2((unsigned)esrc[k] | ((unsigned)(edst[k] & (BNODES - 1)) << 17),
                       (unsigned)bb);
      }
    }
    __syncthreads();

    for (int b = t; b < NB; b += 256) {
      int cnt = lh[b];
      if (cnt) gb[b] = atomicAdd(&gcursor[b], cnt);
    }
    __syncthreads();

    // consecutive i -> same bucket -> coalesced full-line bursts
    for (int i = t; i < total; i += 256) {
      uint2 pr = stage[i];
      int b = (int)pr.y;
      int idx = gb[b] + (i - ls[b]);
      if (idx < BCAP) binned[b * BCAP + idx] = pr.x;   // clamp: never corrupt neighbors
    }
  }
}

// ---------------- K2: FUSED per-bucket sort + aggregate + ELU ------------------
// R22 lesson: k_sa was wave-starved (782 blocks x 4 waves = 12 waves/CU, 37.5%
// occupancy ceiling) while gather-latency-bound. Block size 256 -> 512: same
// grid, 24 waves/CU resident (75% ceiling), 2x latency hiding. Phase 1 NSLOT
// 10 -> 5; phase 2 = 16 half-waves x 8 rounds. Logic otherwise identical.
__global__ __launch_bounds__(512) void k_sa(const int* __restrict__ gcursor,
                                            const unsigned* __restrict__ binned,
                                            const float* __restrict__ s_i,
                                            const float* __restrict__ s_j,
                                            const unsigned short* __restrict__ Wxh,
                                            float* __restrict__ out) {
  __shared__ int cnt128[BNODES];
  __shared__ int ex128[BNODES];
  __shared__ float sil[BNODES];
  __shared__ float den[BNODES];
  __shared__ float invd[BNODES];
  __shared__ unsigned stage[BCAP];
  __shared__ int sW0;
  const int t = threadIdx.x;
  const int b = blockIdx.x;
  const int n0 = b << BSH;
  const int base = b * BCAP;
  const int cnt = min(gcursor[b], BCAP);

  if (t < BNODES) {
    cnt128[t] = 0;
    den[t] = 0.f;
    int n = n0 + t;
    sil[t] = (n < NN) ? s_i[n] : 0.f;
  }
  __syncthreads();

  // ---- phase 1: load + rank + weight + denom (register-staged) ----
  unsigned es[NSLOT];
  int ed[NSLOT], rk[NSLOT];
  float ws[NSLOT];
  #pragma unroll
  for (int k = 0; k < NSLOT; ++k) {
    int i = t + k * 512;
    bool v = i < cnt;
    unsigned pw = v ? binned[base + i] : 0u;
    es[k] = pw & 0x1ffffu;
    ed[k] = v ? (int)(pw >> 17) : -1;
    ws[k] = 0.f;
    rk[k] = 0;
    if (v) {
      rk[k] = atomicAdd(&cnt128[ed[k]], 1);
      float sc = sil[ed[k]] + s_j[es[k]];
      sc = (sc > 0.f) ? sc : NEG_SLOPE * sc;
      ws[k] = __expf(sc);
      atomicAdd(&den[ed[k]], ws[k]);
    }
  }
  __syncthreads();

  // inverse denom + exclusive scan of counts via 2-wave shfl scan (t < 128)
  int c0 = 0;
  if (t < BNODES) {
    float dv = den[t];
    invd[t] = (dv > 0.f) ? 1.f / dv : 0.f;
    c0 = cnt128[t];
  }
  int incl = c0;
  #pragma unroll
  for (int d = 1; d < 64; d <<= 1) {
    int u = __shfl_up(incl, d);
    if ((t & 63) >= d) incl += u;
  }
  if (t == 63) sW0 = incl;
  __syncthreads();
  if (t < BNODES) ex128[t] = incl - c0 + ((t >= 64) ? sW0 : 0);
  __syncthreads();

  // scatter packed (alpha_hi15 | src) into node-sorted LDS order
  #pragma unroll
  for (int k = 0; k < NSLOT; ++k) {
    if (ed[k] >= 0) {
      float alpha = ws[k] * invd[ed[k]];
      unsigned abits = (__float_as_uint(alpha) + 0x10000u) & 0xfffe0000u;  // RNE to 15b
      stage[ex128[ed[k]] + rk[k]] = abits | es[k];
    }
  }
  __syncthreads();

  // ---- phase 2: 16 half-waves x 8 rounds; 4 edges x 4 quads in flight ----
  const int half = t >> 5;           // 0..15
  const int l32 = t & 31;
  const int g = l32 >> 3;            // quad slot 0..3
  const unsigned cl8 = (l32 & 7) << 3;  // channel octet base

  for (int rnd = 0; rnd < 8; ++rnd) {
    const int dl = rnd * 16 + half;
    const int myCnt = cnt128[dl];
    const int myEx = ex128[dl];
    float acc[8];
    #pragma unroll
    for (int j = 0; j < 8; ++j) acc[j] = 0.f;

    for (int eb = 0; eb < myCnt; eb += 16) {
      int i0 = eb + 4 * g;
      unsigned u0 = (i0 + 0 < myCnt) ? stage[myEx + i0 + 0] : 0u;
      unsigned u1 = (i0 + 1 < myCnt) ? stage[myEx + i0 + 1] : 0u;
      unsigned u2 = (i0 + 2 < myCnt) ? stage[myEx + i0 + 2] : 0u;
      unsigned u3 = (i0 + 3 < myCnt) ? stage[myEx + i0 + 3] : 0u;
      float w0 = __uint_as_float(u0 & 0xfffe0000u);   // pads: +0.0, src 0 (safe)
      float w1 = __uint_as_float(u1 & 0xfffe0000u);
      float w2 = __uint_as_float(u2 & 0xfffe0000u);
      float w3 = __uint_as_float(u3 & 0xfffe0000u);
      uint4 h0 = *reinterpret_cast<const uint4*>(&Wxh[((u0 & 0x1ffffu) << 6) + cl8]);
      uint4 h1 = *reinterpret_cast<const uint4*>(&Wxh[((u1 & 0x1ffffu) << 6) + cl8]);
      uint4 h2 = *reinterpret_cast<const uint4*>(&Wxh[((u2 & 0x1ffffu) << 6) + cl8]);
      uint4 h3 = *reinterpret_cast<const uint4*>(&Wxh[((u3 & 0x1ffffu) << 6) + cl8]);
      acc[0] = fmaf(w0, bf2f(h0.x & 0xffffu), acc[0]);
      acc[1] = fmaf(w0, bf2f(h0.x >> 16), acc[1]);
      acc[2] = fmaf(w0, bf2f(h0.y & 0xffffu), acc[2]);
      acc[3] = fmaf(w0, bf2f(h0.y >> 16), acc[3]);
      acc[4] = fmaf(w0, bf2f(h0.z & 0xffffu), acc[4]);
      acc[5] = fmaf(w0, bf2f(h0.z >> 16), acc[5]);
      acc[6] = fmaf(w0, bf2f(h0.w & 0xffffu), acc[6]);
      acc[7] = fmaf(w0, bf2f(h0.w >> 16), acc[7]);
      acc[0] = fmaf(w1, bf2f(h1.x & 0xffffu), acc[0]);
      acc[1] = fmaf(w1, bf2f(h1.x >> 16), acc[1]);
      acc[2] = fmaf(w1, bf2f(h1.y & 0xffffu), acc[2]);
      acc[3] = fmaf(w1, bf2f(h1.y >> 16), acc[3]);
      acc[4] = fmaf(w1, bf2f(h1.z & 0xffffu), acc[4]);
      acc[5] = fmaf(w1, bf2f(h1.z >> 16), acc[5]);
      acc[6] = fmaf(w1, bf2f(h1.w & 0xffffu), acc[6]);
      acc[7] = fmaf(w1, bf2f(h1.w >> 16), acc[7]);
      acc[0] = fmaf(w2, bf2f(h2.x & 0xffffu), acc[0]);
      acc[1] = fmaf(w2, bf2f(h2.x >> 16), acc[1]);
      acc[2] = fmaf(w2, bf2f(h2.y & 0xffffu), acc[2]);
      acc[3] = fmaf(w2, bf2f(h2.y >> 16), acc[3]);
      acc[4] = fmaf(w2, bf2f(h2.z & 0xffffu), acc[4]);
      acc[5] = fmaf(w2, bf2f(h2.z >> 16), acc[5]);
      acc[6] = fmaf(w2, bf2f(h2.w & 0xffffu), acc[6]);
      acc[7] = fmaf(w2, bf2f(h2.w >> 16), acc[7]);
      acc[0] = fmaf(w3, bf2f(h3.x & 0xffffu), acc[0]);
      acc[1] = fmaf(w3, bf2f(h3.x >> 16), acc[1]);
      acc[2] = fmaf(w3, bf2f(h3.y & 0xffffu), acc[2]);
      acc[3] = fmaf(w3, bf2f(h3.y >> 16), acc[3]);
      acc[4] = fmaf(w3, bf2f(h3.z & 0xffffu), acc[4]);
      acc[5] = fmaf(w3, bf2f(h3.z >> 16), acc[5]);
      acc[6] = fmaf(w3, bf2f(h3.w & 0xffffu), acc[6]);
      acc[7] = fmaf(w3, bf2f(h3.w >> 16), acc[7]);
    }

    #pragma unroll
    for (int m = 8; m <= 16; m <<= 1) {
      #pragma unroll
      for (int j = 0; j < 8; ++j) acc[j] += __shfl_xor(acc[j], m);
    }

    const int n = n0 + dl;
    if (g == 0 && n < NN) {
      float r[8];
      #pragma unroll
      for (int j = 0; j < 8; ++j)
        r[j] = (acc[j] > 0.f) ? acc[j] : __expf(acc[j]) - 1.f;   // elu
      unsigned ob = ((unsigned)n << 6) + cl8;
      *reinterpret_cast<float4*>(&out[ob]) = make_float4(r[0], r[1], r[2], r[3]);
      *reinterpret_cast<float4*>(&out[ob + 4]) = make_float4(r[4], r[5], r[6], r[7]);
    }
  }
}

extern "C" void kernel_launch(void* const* d_in, const int* in_sizes, int n_in,
                              void* d_out, int out_size, void* d_ws, size_t ws_size,
                              hipStream_t stream) {
  const float* x = (const float*)d_in[0];
  const int* edge = (const int*)d_in[1];   // [2, E]: row 0 = src, row 1 = dst
  const float* W = (const float*)d_in[2];
  const float* a = (const float*)d_in[3];
  const int* srcIdx = edge;
  const int* dstIdx = edge + EE;
  float* out = (float*)d_out;

  // workspace layout (~22 MB): sorted4 + offs2 eliminated by the k_sa fusion.
  unsigned short* Wxh = (unsigned short*)d_ws;                     // N*64 bf16 = 12.8 MB
  unsigned* binned = (unsigned*)((char*)d_ws + (size_t)NN * OUTC * 2);  // NB*BCAP*4B = 8.0 MB
  int* gcursor = (int*)(binned + (size_t)NB * BCAP);               // NB
  float* s_i = (float*)(gcursor + NB);                             // N
  float* s_j = s_i + NN;                                           // N

  k_zero<<<1, 256, 0, stream>>>(gcursor);
  k_gb<<<NBLKG, 256, 0, stream>>>(x, W, a, Wxh, s_i, s_j, srcIdx, dstIdx, gcursor, binned);
  k_sa<<<NB, 512, 0, stream>>>(gcursor, binned, s_i, s_j, Wxh, out);
}